// Round 10
// baseline (488.876 us; speedup 1.0000x reference)
//
#include <hip/hip_runtime.h>

#define EPS 1e-5f
#define NRED 65536.0f   // B*H*W = 64*32*32
#define IMST 73984      // 34*34*64 halo image stride (elements)
#define PATCH 8704      // 136 px * 64 ci (swizzled, no pad)
#define PATCH6 13056    // 204 px * 64 ci (6-row patch for convC)

typedef short bf16x8 __attribute__((ext_vector_type(8)));
typedef float f32x4 __attribute__((ext_vector_type(4)));
typedef unsigned short u16;

#define MFMA16(a, b, c) __builtin_amdgcn_mfma_f32_16x16x32_bf16(a, b, c, 0, 0, 0)
// XOR-swizzled LDS patch addressing: kills bank conflicts with zero padding.
#define SWZ(px, oct) ((px) * 64 + (((oct) ^ ((px) & 7)) * 8))

__device__ __forceinline__ u16 f2bf(float x) {  // RNE f32->bf16
  union { float f; unsigned u; } v; v.f = x;
  unsigned r = v.u + 0x7FFF + ((v.u >> 16) & 1);
  return (u16)(r >> 16);
}
__device__ __forceinline__ float bf2f(u16 h) {
  union { unsigned u; float f; } v; v.u = ((unsigned)h) << 16;
  return v.f;
}
__device__ __forceinline__ unsigned pk2(float a, float b) {
  return (unsigned)f2bf(a) | ((unsigned)f2bf(b) << 16);
}

// DPP row-shift reduce over 16-lane rows; sum valid in ln==15. Pure VALU.
template <int CTRL>
__device__ __forceinline__ float dpp_mov(float x) {
  int xi = __builtin_bit_cast(int, x);
  int r = __builtin_amdgcn_update_dpp(0, xi, CTRL, 0xF, 0xF, true);
  return __builtin_bit_cast(float, r);
}
__device__ __forceinline__ float row_reduce16(float x) {
  x += dpp_mov<0x111>(x);
  x += dpp_mov<0x112>(x);
  x += dpp_mov<0x114>(x);
  x += dpp_mov<0x118>(x);
  return x;
}

// ---- swizzled patch staging (4 rows x 34 cols x 64 ci) ----------------------
__device__ __forceinline__ void stage_mask(const u16* __restrict__ src,
                                           u16* __restrict__ shp, int tid, int R0) {
#pragma unroll
  for (int i = 0; i < 5; ++i) {
    int c = i * 256 + tid;
    if (i == 4 && tid >= 64) break;
    int px = c >> 3, oct = c & 7;
    int prow = px / 34, pcol = px - prow * 34;
    bool halo = (R0 + prow == 0) || (R0 + prow == 33) || (pcol == 0) || (pcol == 33);
    uint4 v = {0u, 0u, 0u, 0u};
    if (!halo) v = *(const uint4*)&src[(size_t)c * 8];
    *(uint4*)&shp[SWZ(px, oct)] = v;
  }
}

// Affine staging: h = t*s1[ci]+b1[ci] interior, 0 halo (renorm fused).
__device__ __forceinline__ void stage_affine(const u16* __restrict__ src,
                                             u16* __restrict__ shp, int tid, int R0,
                                             const float* __restrict__ stE) {
  const int oct0 = tid & 7;
  float s[8], bb[8];
#pragma unroll
  for (int j = 0; j < 8; ++j) { s[j] = stE[oct0 * 8 + j]; bb[j] = stE[64 + oct0 * 8 + j]; }
#pragma unroll
  for (int i = 0; i < 5; ++i) {
    int c = i * 256 + tid;
    if (i == 4 && tid >= 64) break;
    int px = c >> 3, oct = c & 7;
    int prow = px / 34, pcol = px - prow * 34;
    bool halo = (R0 + prow == 0) || (R0 + prow == 33) || (pcol == 0) || (pcol == 33);
    uint4 o = {0u, 0u, 0u, 0u};
    if (!halo) {
      uint4 u = *(const uint4*)&src[(size_t)c * 8];
      unsigned uv[4] = {u.x, u.y, u.z, u.w};
      unsigned rv[4];
#pragma unroll
      for (int p2 = 0; p2 < 4; ++p2) {
        float lo = bf2f((u16)(uv[p2] & 0xffff)) * s[p2 * 2] + bb[p2 * 2];
        float hi = bf2f((u16)(uv[p2] >> 16)) * s[p2 * 2 + 1] + bb[p2 * 2 + 1];
        rv[p2] = pk2(lo, hi);
      }
      o.x = rv[0]; o.y = rv[1]; o.z = rv[2]; o.w = rv[3];
    }
    *(uint4*)&shp[SWZ(px, oct)] = o;
  }
}

// st layout: per edge e at st+e*2048: [0,64) s1 | [64,128) b1 | [128,192) bias2.
// sums layout: [round(2)][edge(2)][s:64|q:64] = 512 floats, zeroed by zero_halo.

__global__ void pack_wT1_k(const float* __restrict__ w0, const float* __restrict__ w1,
                           const float* __restrict__ w2, const float* __restrict__ w3,
                           u16* __restrict__ wT1) {
  int e = blockIdx.x / 9, tap = blockIdx.x % 9;
  const float* w = e == 0 ? w0 : e == 1 ? w1 : e == 2 ? w2 : w3;
  u16* dst = wT1 + e * 36864 + tap * 4096;
  for (int idx = threadIdx.x; idx < 4096; idx += 256) {
    int co = idx >> 6, ci = idx & 63;
    dst[idx] = f2bf(w[(co * 64 + ci) * 9 + tap]);
  }
}

// wG64[e][g*8+tap(0..7)][co64][cig8] and wT8[e][g][co64][cig8] (tap 8)
__global__ void pack_wG_k(const float* __restrict__ w0, const float* __restrict__ w1,
                          const float* __restrict__ w2, const float* __restrict__ w3,
                          u16* __restrict__ wG64, u16* __restrict__ wT8) {
  int e = blockIdx.y;
  const float* w = e == 0 ? w0 : e == 1 ? w1 : e == 2 ? w2 : w3;
  int bx = blockIdx.x;  // 0..71
  int g, tap;
  u16* dst;
  if (bx < 64) { g = bx >> 3; tap = bx & 7; dst = wG64 + e * 32768 + bx * 512; }
  else         { g = bx - 64; tap = 8;      dst = wT8 + e * 4096 + g * 512; }
  for (int idx = threadIdx.x; idx < 512; idx += 256) {
    int co = idx >> 3, cig = idx & 7;
    dst[idx] = f2bf(w[(co * 64 + g * 8 + cig) * 9 + tap]);
  }
}

// x (NCHW f32) -> xT = bf16(relu(x)) halo pixel-major (interior only).
__global__ __launch_bounds__(256) void transpose_k(const float* __restrict__ x,
                                                   u16* __restrict__ xT) {
  __shared__ __align__(16) u16 sh[64 * 72];
  const int tid = threadIdx.x;
  const int b = blockIdx.x >> 4, slab = blockIdx.x & 15;
  const int ln = tid & 63, w = tid >> 6;
  const float* xb = x + (size_t)b * 65536 + slab * 64;
#pragma unroll
  for (int i = 0; i < 16; ++i) {
    int ci = w + i * 4;
    float v = xb[ci * 1024 + ln];
    sh[ln * 72 + ci] = f2bf(fmaxf(v, 0.f));
  }
  __syncthreads();
  u16* dst = xT + (size_t)b * IMST;
#pragma unroll
  for (int j = 0; j < 2; ++j) {
    int idx = tid + j * 256;
    int p = idx >> 3, oct = idx & 7;
    int gp = slab * 64 + p;
    int R = gp >> 5, C = gp & 31;
    *(uint4*)&dst[((R + 1) * 34 + C + 1) * 64 + oct * 8] = *(const uint4*)&sh[p * 72 + oct * 8];
  }
}

// zero halo strips of n1T (pool path) + zero the atomic stats accumulators.
__global__ void zero_halo_k(u16* __restrict__ buf, float* __restrict__ sums) {
  int b = blockIdx.x, tid = threadIdx.x;
  if (b == 0 && tid < 128) {
    sums[tid] = 0.f; sums[128 + tid] = 0.f;
    sums[256 + tid] = 0.f; sums[384 + tid] = 0.f;
  }
  if (tid >= 132) return;
  int R, C;
  if (tid < 34) { R = 0; C = tid; }
  else if (tid < 68) { R = 33; C = tid - 34; }
  else if (tid < 100) { R = tid - 67; C = 0; }
  else { R = tid - 99; C = 33; }
  u16* p = buf + (size_t)b * IMST + (size_t)(R * 34 + C) * 64;
  uint4 z = {0u, 0u, 0u, 0u};
#pragma unroll
  for (int i = 0; i < 8; ++i) *(uint4*)&p[i * 8] = z;
}

// ---------------- convA (2-edge batched): t = conv3x3(xin, W1) + stats -------
// A-fragments streamed from global per tap. Stats: per-block LDS reduction then
// 128 global atomicAdds into sums (replaces pA + the 128-block reducerA kernel).
__global__ __launch_bounds__(256, 4) void convA_k(const u16* __restrict__ in0,
                                                  const u16* __restrict__ in1,
                                                  const u16* __restrict__ wTa,
                                                  const u16* __restrict__ wTb,
                                                  u16* __restrict__ t0,
                                                  u16* __restrict__ t1,
                                                  float* __restrict__ sums) {
  __shared__ __align__(16) u16 shp[PATCH];
  __shared__ float sA[64], qA[64];
  const int tid = threadIdx.x;
  const int b = blockIdx.y, R0 = blockIdx.x * 2, z = blockIdx.z;
  const u16* xin = z ? in1 : in0;
  const u16* wT = z ? wTb : wTa;
  u16* t = z ? t1 : t0;
  if (tid < 64) { sA[tid] = 0.f; qA[tid] = 0.f; }
  stage_mask(xin + (size_t)b * IMST + (size_t)R0 * 2176, shp, tid, R0);
  const int lane = tid & 63, w = tid >> 6;
  const int ln = lane & 15, quad = lane >> 4;
  const int lr = w >> 1, mh = w & 1;
  const u16* wbase = wT + (size_t)((mh * 2) * 16 + ln) * 64 + quad * 8;
  __syncthreads();
  f32x4 acc[2][2];
#pragma unroll
  for (int m2 = 0; m2 < 2; ++m2)
#pragma unroll
    for (int nf = 0; nf < 2; ++nf) acc[m2][nf] = (f32x4){0.f, 0.f, 0.f, 0.f};
#pragma unroll 3
  for (int tap = 0; tap < 9; ++tap) {
    const int dy = tap / 3, dx = tap % 3;
    const int px0 = (lr + dy) * 34 + ln + dx;
    bf16x8 A[2][2];
#pragma unroll
    for (int m2 = 0; m2 < 2; ++m2)
#pragma unroll
      for (int h = 0; h < 2; ++h)
        A[m2][h] = *(const bf16x8*)&wbase[(size_t)(tap * 64 + m2 * 16) * 64 + h * 32];
#pragma unroll
    for (int h = 0; h < 2; ++h) {
      const int oct = h * 4 + quad;
      bf16x8 b0 = *(const bf16x8*)&shp[SWZ(px0, oct)];
      bf16x8 b1 = *(const bf16x8*)&shp[SWZ(px0 + 16, oct)];
      acc[0][0] = MFMA16(A[0][h], b0, acc[0][0]);
      acc[0][1] = MFMA16(A[0][h], b1, acc[0][1]);
      acc[1][0] = MFMA16(A[1][h], b0, acc[1][0]);
      acc[1][1] = MFMA16(A[1][h], b1, acc[1][1]);
    }
  }
  const int R = R0 + lr;
#pragma unroll
  for (int m2 = 0; m2 < 2; ++m2) {
    const int cob = (mh * 2 + m2) * 16 + quad * 4;
#pragma unroll
    for (int nf = 0; nf < 2; ++nf) {
      u16* tb = t + (size_t)b * IMST + (size_t)((R + 1) * 34 + nf * 16 + ln + 1) * 64 + cob;
      uint2 pk;
      pk.x = pk2(acc[m2][nf][0], acc[m2][nf][1]);
      pk.y = pk2(acc[m2][nf][2], acc[m2][nf][3]);
      *(uint2*)tb = pk;
    }
#pragma unroll
    for (int r = 0; r < 4; ++r) {
      float v0 = acc[m2][0][r], v1 = acc[m2][1][r];
      float s = row_reduce16(v0) + row_reduce16(v1);
      float q = row_reduce16(v0 * v0) + row_reduce16(v1 * v1);
      if (ln == 15) {
        atomicAdd(&sA[cob + r], s);
        atomicAdd(&qA[cob + r], q);
      }
    }
  }
  __syncthreads();
  if (tid < 64) atomicAdd(&sums[z * 128 + tid], sA[tid]);
  else if (tid < 128) atomicAdd(&sums[z * 128 + 64 + (tid - 64)], qA[tid - 64]);
}

// ---------------- convC: 4-row tile, 8 waves, T14 async shA restage ----------
// grid (8, 64, 2): z = edge. s1/b1 finalized per-block from atomic sums into
// LDS stf (deterministic, identical across blocks) -- reducerA eliminated.
// (512,4): r7's (512,6) forced 40-VGPR spill; (512,4) -> clean 52-VGPR alloc.
__global__ __launch_bounds__(512, 4) void convC_k(const u16* __restrict__ t0,
                                                  const u16* __restrict__ t1,
                                                  const u16* __restrict__ wG64,
                                                  const u16* __restrict__ wT8,
                                                  const float* __restrict__ a1,
                                                  const float* __restrict__ sums,
                                                  float* __restrict__ pC) {
  __shared__ __align__(16) u16 shp[PATCH6];       // 26112 B
  __shared__ __align__(16) u16 shA[64 * 16 * 8];  // 16384 B (one co-quarter)
  __shared__ __align__(16) u16 shA2[8 * 16 * 8];  // 2048 B
  __shared__ float sC[4][128], qC[4][128];        // 4096 B
  __shared__ float stf[128];                      // 512 B (s1|b1)
  const int tid = threadIdx.x;
  const int b = blockIdx.y, R0 = blockIdx.x * 4;
  const int edge = blockIdx.z;
  const u16* t = edge ? t1 : t0;
  const u16* wGe = wG64 + edge * 32768;
  const u16* wT8e = wT8 + edge * 4096;
  ((float*)sC)[tid] = 0.f;
  ((float*)qC)[tid] = 0.f;
  if (tid < 64) {  // finalize BN1 from atomic sums (identical across blocks)
    float S = sums[edge * 128 + tid], Q = sums[edge * 128 + 64 + tid];
    int g = tid >> 3;
    float m = 0.f;
    for (int i = g; i < 8; ++i) m += a1[i];
    float mu = S * (1.f / NRED);
    float var = Q * (1.f / NRED) - mu * mu;
    float rr = rsqrtf(var + EPS);
    stf[tid] = rr * m;
    stf[64 + tid] = -mu * rr * m;
  }
  __syncthreads();
  // ---- stage 6-row affine patch (1632 chunks, 512 threads) ----
  {
    const int oct0 = tid & 7;
    float sc[8], bc[8];
#pragma unroll
    for (int j = 0; j < 8; ++j) { sc[j] = stf[oct0 * 8 + j]; bc[j] = stf[64 + oct0 * 8 + j]; }
    const u16* src = t + (size_t)b * IMST + (size_t)R0 * 2176;
#pragma unroll
    for (int i = 0; i < 4; ++i) {
      int c = i * 512 + tid;
      if (i == 3 && tid >= 96) break;
      int px = c >> 3, oct = c & 7;
      int prow = px / 34, pcol = px - prow * 34;
      bool halo = (R0 + prow == 0) || (R0 + prow == 33) || (pcol == 0) || (pcol == 33);
      uint4 o = {0u, 0u, 0u, 0u};
      if (!halo) {
        uint4 u = *(const uint4*)&src[(size_t)c * 8];
        unsigned uv[4] = {u.x, u.y, u.z, u.w};
        unsigned rv[4];
#pragma unroll
        for (int p2 = 0; p2 < 4; ++p2) {
          float lo = bf2f((u16)(uv[p2] & 0xffff)) * sc[p2 * 2] + bc[p2 * 2];
          float hi = bf2f((u16)(uv[p2] >> 16)) * sc[p2 * 2 + 1] + bc[p2 * 2 + 1];
          rv[p2] = pk2(lo, hi);
        }
        o.x = rv[0]; o.y = rv[1]; o.z = rv[2]; o.w = rv[3];
      }
      *(uint4*)&shp[SWZ(px, oct)] = o;
    }
  }
  // ---- stage shA/shA2 for coq=0 (1024 chunks / 128 chunks) ----
#pragma unroll
  for (int i = 0; i < 2; ++i) {
    int c = i * 512 + tid;
    int row = c >> 4, col = c & 15;
    *(uint4*)&shA[c * 8] = *(const uint4*)&wGe[(size_t)(row * 64 + col) * 8];
  }
  if (tid < 128) {
    int g = tid >> 4, col = tid & 15;
    *(uint4*)&shA2[tid * 8] = *(const uint4*)&wT8e[(size_t)(g * 64 + col) * 8];
  }
  __syncthreads();
  const int lane = tid & 63, w = tid >> 6;
  const int ln = lane & 15, quad = lane >> 4;
  const int lrow = w >> 1, colbase = (w & 1) * 16;
  int px[3];
#pragma unroll
  for (int ch = 0; ch < 3; ++ch) {
    int tp = ch * 4 + quad; if (tp > 8) tp = 8;
    px[ch] = (lrow + tp / 3) * 34 + colbase + ln + tp % 3;
  }
#pragma unroll 1
  for (int coq = 0; coq < 4; ++coq) {
    // T14: issue next co-quarter's weight loads into regs before compute
    uint4 wr0, wr1, wr2;
    if (coq < 3) {
      const int nq = coq + 1;
      {
        int c = tid;
        wr0 = *(const uint4*)&wGe[(size_t)((c >> 4) * 64 + nq * 16 + (c & 15)) * 8];
      }
      {
        int c = 512 + tid;
        wr1 = *(const uint4*)&wGe[(size_t)((c >> 4) * 64 + nq * 16 + (c & 15)) * 8];
      }
      if (tid < 128)
        wr2 = *(const uint4*)&wT8e[(size_t)((tid >> 4) * 64 + nq * 16 + (tid & 15)) * 8];
    }
    f32x4 acc[8];
#pragma unroll
    for (int g = 0; g < 8; ++g) acc[g] = (f32x4){0.f, 0.f, 0.f, 0.f};
#pragma unroll
    for (int g = 0; g < 8; ++g) {
#pragma unroll
      for (int ch = 0; ch < 3; ++ch) {
        bf16x8 bx = *(const bf16x8*)&shp[SWZ(px[ch], g)];
        bf16x8 aw;
        if (ch < 2) {
          aw = *(const bf16x8*)&shA[((g * 8 + ch * 4 + quad) * 16 + ln) * 8];
        } else {
          aw = (bf16x8){0, 0, 0, 0, 0, 0, 0, 0};
          if (quad == 0) aw = *(const bf16x8*)&shA2[(g * 16 + ln) * 8];
        }
        acc[g] = MFMA16(aw, bx, acc[g]);
      }
    }
    f32x4 P = (f32x4){0.f, 0.f, 0.f, 0.f};
#pragma unroll
    for (int k = 0; k < 8; ++k) {
      P += acc[k];
#pragma unroll
      for (int r = 0; r < 4; ++r) {
        float v = P[r];
        float s = row_reduce16(v);
        float q = row_reduce16(v * v);
        if (ln == 15) {
          atomicAdd(&sC[coq][k * 16 + quad * 4 + r], s);
          atomicAdd(&qC[coq][k * 16 + quad * 4 + r], q);
        }
      }
    }
    __syncthreads();  // all reads of shA/shA2 for this coq done
    if (coq < 3) {    // write prefetched regs -> LDS
      *(uint4*)&shA[(size_t)tid * 8] = wr0;
      *(uint4*)&shA[(size_t)(512 + tid) * 8] = wr1;
      if (tid < 128) *(uint4*)&shA2[tid * 8] = wr2;
      __syncthreads();
    }
  }
  __syncthreads();
  const int blk = blockIdx.y * 8 + blockIdx.x;  // 0..511
#pragma unroll 1
  for (int coq = 0; coq < 4; ++coq) {
    const size_t base = ((size_t)(edge * 4 + coq) * 512 + blk) * 256;
    if (tid < 128) pC[base + tid] = sC[coq][tid];
    else if (tid < 256) pC[base + 128 + (tid - 128)] = qC[coq][tid - 128];
  }
}

// redCprepE (batched): grid (64, 2): c, z(edge). finalizeC + fold g -> wE.
// Also writes s1/b1 into stE from atomic sums (for convE/convE23 consumers).
__global__ __launch_bounds__(256) void redCprepE_k(const float* __restrict__ pC,
                                                   const float* __restrict__ w2a,
                                                   const float* __restrict__ w2b,
                                                   const float* __restrict__ a1,
                                                   const float* __restrict__ a2,
                                                   const float* __restrict__ sums,
                                                   float* __restrict__ stBase,
                                                   u16* __restrict__ wEbase,
                                                   float* __restrict__ cm) {
  const int tid = threadIdx.x, c = blockIdx.x, z = blockIdx.y;
  const int coq = c >> 4, cl = c & 15;
  const float* w2 = z ? w2b : w2a;
  float* stE = stBase + z * 2048;
  u16* wE = wEbase + z * 36864;
  if (tid == 0) {  // finalize BN1 s1/b1 for this channel (was reducerA)
    float S = sums[z * 128 + c], Q = sums[z * 128 + 64 + c];
    int g = c >> 3;
    float m = 0.f;
    for (int i = g; i < 8; ++i) m += a1[i];
    float mu = S * (1.f / NRED);
    float var = Q * (1.f / NRED) - mu * mu;
    float rr = rsqrtf(var + EPS);
    stE[c] = rr * m;
    stE[64 + c] = -mu * rr * m;
  }
  float s[8], q[8];
#pragma unroll
  for (int k = 0; k < 8; ++k) { s[k] = 0.f; q[k] = 0.f; }
  for (int i = tid; i < 512; i += 256) {
    const float* pb = pC + ((size_t)(z * 4 + coq) * 512 + i) * 256;
#pragma unroll
    for (int k = 0; k < 8; ++k) {
      s[k] += pb[k * 16 + cl];
      q[k] += pb[128 + k * 16 + cl];
    }
  }
#pragma unroll
  for (int k = 0; k < 8; ++k) {
#pragma unroll
    for (int off = 32; off; off >>= 1) { s[k] += __shfl_xor(s[k], off); q[k] += __shfl_xor(q[k], off); }
  }
  __shared__ float red[4][16];
  __shared__ float gL[8];
  int wv = tid >> 6;
  if ((tid & 63) == 0) {
#pragma unroll
    for (int k = 0; k < 8; ++k) { red[wv][k * 2] = s[k]; red[wv][k * 2 + 1] = q[k]; }
  }
  __syncthreads();
  if (tid == 0) {
    float suf = 0.f, bias = 0.f;
    for (int k = 7; k >= 0; --k) {
      float S = red[0][k * 2] + red[1][k * 2] + red[2][k * 2] + red[3][k * 2];
      float Q = red[0][k * 2 + 1] + red[1][k * 2 + 1] + red[2][k * 2 + 1] + red[3][k * 2 + 1];
      float mu = S * (1.f / NRED);
      float var = Q * (1.f / NRED) - mu * mu;
      float rr = rsqrtf(var + EPS);
      bias -= a2[k] * mu * rr;
      suf += a2[k] * rr;
      gL[k] = suf;
    }
    stE[128 + c] = bias;
    if (z == 0) {
      int g = c >> 3;
      float m1 = 0.f, m2 = 0.f;
      for (int i = g; i < 8; ++i) { m1 += a1[i]; m2 += a2[i]; }
      cm[c] = m1 * m2;
    }
  }
  __syncthreads();
  for (int idx = tid; idx < 576; idx += 256) {
    int tap = idx >> 6, ci = idx & 63;
    wE[(tap * 64 + c) * 64 + ci] = f2bf(w2[(c * 64 + ci) * 9 + tap] * gL[ci >> 3]);
  }
}

// ---------------- convE (modes 0,1): conv2 + epilogue ------------------------
// A-fragments streamed from global per tap (same coalesced layout as convA).
// MODE 1: n1T pool neighborhood staged raw into LDS shn (r9: -14us).
template <int MODE>
__global__ __launch_bounds__(256, 4) void convE_k(const u16* __restrict__ t,
                                                  const float* __restrict__ stE,
                                                  const u16* __restrict__ wEp,
                                                  u16* __restrict__ d1,
                                                  u16* __restrict__ d2,
                                                  const float* __restrict__ cm) {
  __shared__ __align__(16) u16 shp[PATCH];
  __shared__ __align__(16) u16 shn[MODE == 1 ? PATCH : 8];
  __shared__ float cmL[64], biasL[64];
  const int tid = threadIdx.x;
  const int b = blockIdx.y, R0 = blockIdx.x * 2;
  if (tid < 64) { cmL[tid] = cm[tid]; biasL[tid] = stE[128 + tid]; }
  stage_affine(t + (size_t)b * IMST + (size_t)R0 * 2176, shp, tid, R0, stE);
  if constexpr (MODE == 1) {
    const u16* nsrc = d2 + (size_t)b * IMST + (size_t)R0 * 2176;
#pragma unroll
    for (int i = 0; i < 5; ++i) {
      int c = i * 256 + tid;
      if (i == 4 && tid >= 64) break;
      int px = c >> 3, oct = c & 7;
      *(uint4*)&shn[SWZ(px, oct)] = *(const uint4*)&nsrc[(size_t)c * 8];
    }
  }
  const int lane = tid & 63, w = tid >> 6;
  const int ln = lane & 15, quad = lane >> 4;
  const int lr = w >> 1, mh = w & 1;
  const u16* wbase = wEp + (size_t)((mh * 2) * 16 + ln) * 64 + quad * 8;
  __syncthreads();
  f32x4 acc[2][2];
#pragma unroll
  for (int m2 = 0; m2 < 2; ++m2)
#pragma unroll
    for (int nf = 0; nf < 2; ++nf) acc[m2][nf] = (f32x4){0.f, 0.f, 0.f, 0.f};
#pragma unroll 3
  for (int tap = 0; tap < 9; ++tap) {
    const int dy = tap / 3, dx = tap % 3;
    const int px0 = (lr + dy) * 34 + ln + dx;
    bf16x8 A[2][2];
#pragma unroll
    for (int m2 = 0; m2 < 2; ++m2)
#pragma unroll
      for (int h = 0; h < 2; ++h)
        A[m2][h] = *(const bf16x8*)&wbase[(size_t)(tap * 64 + m2 * 16) * 64 + h * 32];
#pragma unroll
    for (int h = 0; h < 2; ++h) {
      const int oct = h * 4 + quad;
      bf16x8 b0 = *(const bf16x8*)&shp[SWZ(px0, oct)];
      bf16x8 b1 = *(const bf16x8*)&shp[SWZ(px0 + 16, oct)];
      acc[0][0] = MFMA16(A[0][h], b0, acc[0][0]);
      acc[0][1] = MFMA16(A[0][h], b1, acc[0][1]);
      acc[1][0] = MFMA16(A[1][h], b0, acc[1][0]);
      acc[1][1] = MFMA16(A[1][h], b1, acc[1][1]);
    }
  }
  const int R = R0 + lr;
#pragma unroll
  for (int m2 = 0; m2 < 2; ++m2) {
    const int cob = (mh * 2 + m2) * 16 + quad * 4;
#pragma unroll
    for (int nf = 0; nf < 2; ++nf) {
      const int C = nf * 16 + ln;
      const size_t haloPx = (size_t)b * IMST + (size_t)((R + 1) * 34 + C + 1) * 64 + cob;
      float v[4];
#pragma unroll
      for (int r = 0; r < 4; ++r) v[r] = acc[m2][nf][r] + biasL[cob + r];
      if (MODE == 0) {
        uint2 pk, pkr;
        pk.x = pk2(v[0], v[1]); pk.y = pk2(v[2], v[3]);
        pkr.x = pk2(fmaxf(v[0], 0.f), fmaxf(v[1], 0.f));
        pkr.y = pk2(fmaxf(v[2], 0.f), fmaxf(v[3], 0.f));
        *(uint2*)&d1[haloPx] = pk;    // n1T (raw, for pool)
        *(uint2*)&d2[haloPx] = pkr;   // n1r (relu, e2 input)
      } else {
        float ps[4] = {0.f, 0.f, 0.f, 0.f};
#pragma unroll
        for (int dy = 0; dy < 3; ++dy)
#pragma unroll
          for (int dx = 0; dx < 3; ++dx) {
            const int ppx = (lr + dy) * 34 + C + dx;
            uint2 u = *(const uint2*)&shn[SWZ(ppx, cob >> 3) + (cob & 7)];
            ps[0] += bf2f((u16)(u.x & 0xffff));
            ps[1] += bf2f((u16)(u.x >> 16));
            ps[2] += bf2f((u16)(u.y & 0xffff));
            ps[3] += bf2f((u16)(u.y >> 16));
          }
        float rows = 3.f - (R == 0 ? 1.f : 0.f) - (R == 31 ? 1.f : 0.f);
        float cols = 3.f - (C == 0 ? 1.f : 0.f) - (C == 31 ? 1.f : 0.f);
        float inv = 1.f / (rows * cols);
        uint2 pkr;
        float t0v = fmaxf(v[0] + ps[0] * inv * cmL[cob], 0.f);
        float t1v = fmaxf(v[1] + ps[1] * inv * cmL[cob + 1], 0.f);
        float t2v = fmaxf(v[2] + ps[2] * inv * cmL[cob + 2], 0.f);
        float t3v = fmaxf(v[3] + ps[3] * inv * cmL[cob + 3], 0.f);
        pkr.x = pk2(t0v, t1v); pkr.y = pk2(t2v, t3v);
        *(uint2*)&d1[haloPx] = pkr;   // n2r
      }
    }
  }
}

// ---------------- convE23: fused final two convs + output --------------------
__global__ __launch_bounds__(256, 4) void convE23_k(const u16* __restrict__ t0,
                                                    const u16* __restrict__ t1,
                                                    const float* __restrict__ stBase,
                                                    const u16* __restrict__ wE2,
                                                    const u16* __restrict__ wE3,
                                                    float* __restrict__ outp,
                                                    const float* __restrict__ x,
                                                    const float* __restrict__ cm) {
  __shared__ __align__(16) u16 shp2[2 * PATCH];
  __shared__ float cmL[64], biasL[64];
  const int tid = threadIdx.x;
  const int b = blockIdx.y, R0 = blockIdx.x * 2;
  if (tid < 64) {
    cmL[tid] = cm[tid];
    biasL[tid] = stBase[128 + tid] + stBase[2048 + 128 + tid];
  }
  stage_affine(t0 + (size_t)b * IMST + (size_t)R0 * 2176, shp2, tid, R0, stBase);
  stage_affine(t1 + (size_t)b * IMST + (size_t)R0 * 2176, shp2 + PATCH, tid, R0, stBase + 2048);
  __syncthreads();
  const int lane = tid & 63, w = tid >> 6;
  const int ln = lane & 15, quad = lane >> 4;
  const int lr = w >> 1, mh = w & 1;
  f32x4 acc[2][2];
#pragma unroll
  for (int m2 = 0; m2 < 2; ++m2)
#pragma unroll
    for (int nf = 0; nf < 2; ++nf) acc[m2][nf] = (f32x4){0.f, 0.f, 0.f, 0.f};
#pragma unroll 1
  for (int ei = 0; ei < 2; ++ei) {
    const u16* wEp = ei ? wE3 : wE2;
    const u16* sp = &shp2[ei * PATCH];
    const u16* wbase = wEp + (size_t)((mh * 2) * 16 + ln) * 64 + quad * 8;
#pragma unroll 3
    for (int tap = 0; tap < 9; ++tap) {
      const int dy = tap / 3, dx = tap % 3;
      const int px0 = (lr + dy) * 34 + ln + dx;
      bf16x8 A[2][2];
#pragma unroll
      for (int m2 = 0; m2 < 2; ++m2)
#pragma unroll
        for (int h = 0; h < 2; ++h)
          A[m2][h] = *(const bf16x8*)&wbase[(size_t)(tap * 64 + m2 * 16) * 64 + h * 32];
#pragma unroll
      for (int h = 0; h < 2; ++h) {
        const int oct = h * 4 + quad;
        bf16x8 b0 = *(const bf16x8*)&sp[SWZ(px0, oct)];
        bf16x8 b1 = *(const bf16x8*)&sp[SWZ(px0 + 16, oct)];
        acc[0][0] = MFMA16(A[0][h], b0, acc[0][0]);
        acc[0][1] = MFMA16(A[0][h], b1, acc[0][1]);
        acc[1][0] = MFMA16(A[1][h], b0, acc[1][0]);
        acc[1][1] = MFMA16(A[1][h], b1, acc[1][1]);
      }
    }
  }
  const int R = R0 + lr;
#pragma unroll
  for (int m2 = 0; m2 < 2; ++m2) {
    const int cob = (mh * 2 + m2) * 16 + quad * 4;
#pragma unroll
    for (int nf = 0; nf < 2; ++nf) {
      const int C = nf * 16 + ln;
      size_t base = (size_t)b * 65536 + (size_t)cob * 1024 + R * 32 + C;
#pragma unroll
      for (int r = 0; r < 4; ++r)
        outp[base + (size_t)r * 1024] =
            acc[m2][nf][r] + biasL[cob + r] + x[base + (size_t)r * 1024] * cmL[cob + r];
    }
  }
}

extern "C" void kernel_launch(void* const* d_in, const int* in_sizes, int n_in,
                              void* d_out, int out_size, void* d_ws, size_t ws_size,
                              hipStream_t stream) {
  const float* x  = (const float*)d_in[0];
  const float* a1 = (const float*)d_in[1];
  const float* a2 = (const float*)d_in[2];
  const float* W1[4] = {(const float*)d_in[3], (const float*)d_in[5],
                        (const float*)d_in[7], (const float*)d_in[9]};
  const float* W2[4] = {(const float*)d_in[4], (const float*)d_in[6],
                        (const float*)d_in[8], (const float*)d_in[10]};
  float* out = (float*)d_out;
  char* ws = (char*)d_ws;
  const size_t HB = (size_t)IMST * 64 * 2;  // 9,469,952 B per halo buffer
  u16* xT  = (u16*)ws;
  u16* t0  = (u16*)(ws + HB);
  u16* t1  = (u16*)(ws + 2 * HB);
  u16* n1T = (u16*)(ws + 3 * HB);
  u16* n1r = (u16*)(ws + 4 * HB);
  u16* n2r = (u16*)(ws + 5 * HB);
  char* p = ws + 6 * HB;
  float* st  = (float*)p;            p += 8256 * 4;
  u16* wT1   = (u16*)p;              p += 4 * 36864 * 2;
  u16* wG64  = (u16*)p;              p += 4 * 32768 * 2;
  u16* wT8   = (u16*)p;              p += 4 * 4096 * 2;
  u16* wE    = (u16*)p;              p += 4 * 36864 * 2;
  float* sums = (float*)p;           p += 512 * 4;   // [round][edge][s|q]
  float* pC  = (float*)p;            // 8 * 512 * 256 * 4 = 4 MB
  float* cm  = st + 8192;

  pack_wT1_k<<<36, 256, 0, stream>>>(W1[0], W1[1], W1[2], W1[3], wT1);
  pack_wG_k<<<dim3(72, 4), 256, 0, stream>>>(W2[0], W2[1], W2[2], W2[3], wG64, wT8);
  transpose_k<<<1024, 256, 0, stream>>>(x, xT);
  zero_halo_k<<<64, 160, 0, stream>>>(n1T, sums);

  dim3 gA(16, 64, 2), gC(8, 64, 2), gE(16, 64);
  // batch edges 0+1 (both consume xT)
  convA_k<<<gA, 256, 0, stream>>>(xT, xT, wT1, wT1 + 36864, t0, t1, sums);
  convC_k<<<gC, 512, 0, stream>>>(t0, t1, wG64, wT8, a1, sums, pC);
  redCprepE_k<<<dim3(64, 2), 256, 0, stream>>>(pC, W2[0], W2[1], a1, a2, sums, st, wE, cm);
  convE_k<0><<<gE, 256, 0, stream>>>(t0, st, wE, n1T, n1r, cm);
  convE_k<1><<<gE, 256, 0, stream>>>(t1, st + 2048, wE + 36864, n2r, n1T, cm);
  // batch edges 2+3 (consume n1r, n2r)
  convA_k<<<gA, 256, 0, stream>>>(n1r, n2r, wT1 + 2 * 36864, wT1 + 3 * 36864, t0, t1,
                                  sums + 256);
  convC_k<<<gC, 512, 0, stream>>>(t0, t1, wG64 + 2 * 32768, wT8 + 2 * 4096, a1,
                                  sums + 256, pC);
  redCprepE_k<<<dim3(64, 2), 256, 0, stream>>>(pC, W2[2], W2[3], a1, a2, sums + 256,
                                               st + 4096, wE + 2 * 36864, cm);
  convE23_k<<<gE, 256, 0, stream>>>(t0, t1, st + 4096, wE + 2 * 36864, wE + 3 * 36864,
                                    out, x, cm);
}

// Round 11
// 434.548 us; speedup vs baseline: 1.1250x; 1.1250x over previous
//
#include <hip/hip_runtime.h>

#define EPS 1e-5f
#define NRED 65536.0f   // B*H*W = 64*32*32
#define IMST 73984      // 34*34*64 halo image stride (elements)
#define PATCH 8704      // 136 px * 64 ci (swizzled, no pad)
#define PATCH6 13056    // 204 px * 64 ci (6-row patch for convC)

typedef short bf16x8 __attribute__((ext_vector_type(8)));
typedef float f32x4 __attribute__((ext_vector_type(4)));
typedef unsigned short u16;

#define MFMA16(a, b, c) __builtin_amdgcn_mfma_f32_16x16x32_bf16(a, b, c, 0, 0, 0)
// XOR-swizzled LDS patch addressing: kills bank conflicts with zero padding.
#define SWZ(px, oct) ((px) * 64 + (((oct) ^ ((px) & 7)) * 8))

__device__ __forceinline__ u16 f2bf(float x) {  // RNE f32->bf16
  union { float f; unsigned u; } v; v.f = x;
  unsigned r = v.u + 0x7FFF + ((v.u >> 16) & 1);
  return (u16)(r >> 16);
}
__device__ __forceinline__ float bf2f(u16 h) {
  union { unsigned u; float f; } v; v.u = ((unsigned)h) << 16;
  return v.f;
}
__device__ __forceinline__ unsigned pk2(float a, float b) {
  return (unsigned)f2bf(a) | ((unsigned)f2bf(b) << 16);
}

// DPP row-shift reduce over 16-lane rows; sum valid in ln==15. Pure VALU.
template <int CTRL>
__device__ __forceinline__ float dpp_mov(float x) {
  int xi = __builtin_bit_cast(int, x);
  int r = __builtin_amdgcn_update_dpp(0, xi, CTRL, 0xF, 0xF, true);
  return __builtin_bit_cast(float, r);
}
__device__ __forceinline__ float row_reduce16(float x) {
  x += dpp_mov<0x111>(x);
  x += dpp_mov<0x112>(x);
  x += dpp_mov<0x114>(x);
  x += dpp_mov<0x118>(x);
  return x;
}

// ---- swizzled patch staging (4 rows x 34 cols x 64 ci) ----------------------
__device__ __forceinline__ void stage_mask(const u16* __restrict__ src,
                                           u16* __restrict__ shp, int tid, int R0) {
#pragma unroll
  for (int i = 0; i < 5; ++i) {
    int c = i * 256 + tid;
    if (i == 4 && tid >= 64) break;
    int px = c >> 3, oct = c & 7;
    int prow = px / 34, pcol = px - prow * 34;
    bool halo = (R0 + prow == 0) || (R0 + prow == 33) || (pcol == 0) || (pcol == 33);
    uint4 v = {0u, 0u, 0u, 0u};
    if (!halo) v = *(const uint4*)&src[(size_t)c * 8];
    *(uint4*)&shp[SWZ(px, oct)] = v;
  }
}

// Affine staging: h = t*s1[ci]+b1[ci] interior, 0 halo (renorm fused).
__device__ __forceinline__ void stage_affine(const u16* __restrict__ src,
                                             u16* __restrict__ shp, int tid, int R0,
                                             const float* __restrict__ stE) {
  const int oct0 = tid & 7;
  float s[8], bb[8];
#pragma unroll
  for (int j = 0; j < 8; ++j) { s[j] = stE[oct0 * 8 + j]; bb[j] = stE[64 + oct0 * 8 + j]; }
#pragma unroll
  for (int i = 0; i < 5; ++i) {
    int c = i * 256 + tid;
    if (i == 4 && tid >= 64) break;
    int px = c >> 3, oct = c & 7;
    int prow = px / 34, pcol = px - prow * 34;
    bool halo = (R0 + prow == 0) || (R0 + prow == 33) || (pcol == 0) || (pcol == 33);
    uint4 o = {0u, 0u, 0u, 0u};
    if (!halo) {
      uint4 u = *(const uint4*)&src[(size_t)c * 8];
      unsigned uv[4] = {u.x, u.y, u.z, u.w};
      unsigned rv[4];
#pragma unroll
      for (int p2 = 0; p2 < 4; ++p2) {
        float lo = bf2f((u16)(uv[p2] & 0xffff)) * s[p2 * 2] + bb[p2 * 2];
        float hi = bf2f((u16)(uv[p2] >> 16)) * s[p2 * 2 + 1] + bb[p2 * 2 + 1];
        rv[p2] = pk2(lo, hi);
      }
      o.x = rv[0]; o.y = rv[1]; o.z = rv[2]; o.w = rv[3];
    }
    *(uint4*)&shp[SWZ(px, oct)] = o;
  }
}

// st layout: per edge e at st+e*2048: [0,64) s1 | [64,128) b1 | [128,192) bias2.

__global__ void pack_wT1_k(const float* __restrict__ w0, const float* __restrict__ w1,
                           const float* __restrict__ w2, const float* __restrict__ w3,
                           u16* __restrict__ wT1) {
  int e = blockIdx.x / 9, tap = blockIdx.x % 9;
  const float* w = e == 0 ? w0 : e == 1 ? w1 : e == 2 ? w2 : w3;
  u16* dst = wT1 + e * 36864 + tap * 4096;
  for (int idx = threadIdx.x; idx < 4096; idx += 256) {
    int co = idx >> 6, ci = idx & 63;
    dst[idx] = f2bf(w[(co * 64 + ci) * 9 + tap]);
  }
}

// wG64[e][g*8+tap(0..7)][co64][cig8] and wT8[e][g][co64][cig8] (tap 8)
__global__ void pack_wG_k(const float* __restrict__ w0, const float* __restrict__ w1,
                          const float* __restrict__ w2, const float* __restrict__ w3,
                          u16* __restrict__ wG64, u16* __restrict__ wT8) {
  int e = blockIdx.y;
  const float* w = e == 0 ? w0 : e == 1 ? w1 : e == 2 ? w2 : w3;
  int bx = blockIdx.x;  // 0..71
  int g, tap;
  u16* dst;
  if (bx < 64) { g = bx >> 3; tap = bx & 7; dst = wG64 + e * 32768 + bx * 512; }
  else         { g = bx - 64; tap = 8;      dst = wT8 + e * 4096 + g * 512; }
  for (int idx = threadIdx.x; idx < 512; idx += 256) {
    int co = idx >> 3, cig = idx & 7;
    dst[idx] = f2bf(w[(co * 64 + g * 8 + cig) * 9 + tap]);
  }
}

// x (NCHW f32) -> xT = bf16(relu(x)) halo pixel-major (interior only).
__global__ __launch_bounds__(256) void transpose_k(const float* __restrict__ x,
                                                   u16* __restrict__ xT) {
  __shared__ __align__(16) u16 sh[64 * 72];
  const int tid = threadIdx.x;
  const int b = blockIdx.x >> 4, slab = blockIdx.x & 15;
  const int ln = tid & 63, w = tid >> 6;
  const float* xb = x + (size_t)b * 65536 + slab * 64;
#pragma unroll
  for (int i = 0; i < 16; ++i) {
    int ci = w + i * 4;
    float v = xb[ci * 1024 + ln];
    sh[ln * 72 + ci] = f2bf(fmaxf(v, 0.f));
  }
  __syncthreads();
  u16* dst = xT + (size_t)b * IMST;
#pragma unroll
  for (int j = 0; j < 2; ++j) {
    int idx = tid + j * 256;
    int p = idx >> 3, oct = idx & 7;
    int gp = slab * 64 + p;
    int R = gp >> 5, C = gp & 31;
    *(uint4*)&dst[((R + 1) * 34 + C + 1) * 64 + oct * 8] = *(const uint4*)&sh[p * 72 + oct * 8];
  }
}

// zero halo strips of n1T (pool reads raw global n1T incl. halo).
__global__ void zero_halo_k(u16* __restrict__ buf) {
  int b = blockIdx.x, tid = threadIdx.x;
  if (tid >= 132) return;
  int R, C;
  if (tid < 34) { R = 0; C = tid; }
  else if (tid < 68) { R = 33; C = tid - 34; }
  else if (tid < 100) { R = tid - 67; C = 0; }
  else { R = tid - 99; C = 33; }
  u16* p = buf + (size_t)b * IMST + (size_t)(R * 34 + C) * 64;
  uint4 z = {0u, 0u, 0u, 0u};
#pragma unroll
  for (int i = 0; i < 8; ++i) *(uint4*)&p[i * 8] = z;
}

// ---------------- convA (2-edge batched): t = conv3x3(xin, W1) + stats -------
// A-fragments streamed from global per tap (coalesced [tap][co][ci] layout,
// L2-resident 147KB) instead of 144-VGPR register cache.
__global__ __launch_bounds__(256, 4) void convA_k(const u16* __restrict__ in0,
                                                  const u16* __restrict__ in1,
                                                  const u16* __restrict__ wTa,
                                                  const u16* __restrict__ wTb,
                                                  u16* __restrict__ t0,
                                                  u16* __restrict__ t1,
                                                  float* __restrict__ pA) {
  __shared__ __align__(16) u16 shp[PATCH];
  __shared__ float sA[64], qA[64];
  const int tid = threadIdx.x;
  const int b = blockIdx.y, R0 = blockIdx.x * 2, z = blockIdx.z;
  const u16* xin = z ? in1 : in0;
  const u16* wT = z ? wTb : wTa;
  u16* t = z ? t1 : t0;
  if (tid < 64) { sA[tid] = 0.f; qA[tid] = 0.f; }
  stage_mask(xin + (size_t)b * IMST + (size_t)R0 * 2176, shp, tid, R0);
  const int lane = tid & 63, w = tid >> 6;
  const int ln = lane & 15, quad = lane >> 4;
  const int lr = w >> 1, mh = w & 1;
  const u16* wbase = wT + (size_t)((mh * 2) * 16 + ln) * 64 + quad * 8;
  __syncthreads();
  f32x4 acc[2][2];
#pragma unroll
  for (int m2 = 0; m2 < 2; ++m2)
#pragma unroll
    for (int nf = 0; nf < 2; ++nf) acc[m2][nf] = (f32x4){0.f, 0.f, 0.f, 0.f};
#pragma unroll 3
  for (int tap = 0; tap < 9; ++tap) {
    const int dy = tap / 3, dx = tap % 3;
    const int px0 = (lr + dy) * 34 + ln + dx;
    bf16x8 A[2][2];
#pragma unroll
    for (int m2 = 0; m2 < 2; ++m2)
#pragma unroll
      for (int h = 0; h < 2; ++h)
        A[m2][h] = *(const bf16x8*)&wbase[(size_t)(tap * 64 + m2 * 16) * 64 + h * 32];
#pragma unroll
    for (int h = 0; h < 2; ++h) {
      const int oct = h * 4 + quad;
      bf16x8 b0 = *(const bf16x8*)&shp[SWZ(px0, oct)];
      bf16x8 b1 = *(const bf16x8*)&shp[SWZ(px0 + 16, oct)];
      acc[0][0] = MFMA16(A[0][h], b0, acc[0][0]);
      acc[0][1] = MFMA16(A[0][h], b1, acc[0][1]);
      acc[1][0] = MFMA16(A[1][h], b0, acc[1][0]);
      acc[1][1] = MFMA16(A[1][h], b1, acc[1][1]);
    }
  }
  const int R = R0 + lr;
#pragma unroll
  for (int m2 = 0; m2 < 2; ++m2) {
    const int cob = (mh * 2 + m2) * 16 + quad * 4;
#pragma unroll
    for (int nf = 0; nf < 2; ++nf) {
      u16* tb = t + (size_t)b * IMST + (size_t)((R + 1) * 34 + nf * 16 + ln + 1) * 64 + cob;
      uint2 pk;
      pk.x = pk2(acc[m2][nf][0], acc[m2][nf][1]);
      pk.y = pk2(acc[m2][nf][2], acc[m2][nf][3]);
      *(uint2*)tb = pk;
    }
#pragma unroll
    for (int r = 0; r < 4; ++r) {
      float v0 = acc[m2][0][r], v1 = acc[m2][1][r];
      float s = row_reduce16(v0) + row_reduce16(v1);
      float q = row_reduce16(v0 * v0) + row_reduce16(v1 * v1);
      if (ln == 15) {
        atomicAdd(&sA[cob + r], s);
        atomicAdd(&qA[cob + r], q);
      }
    }
  }
  __syncthreads();
  const int blk = z * 1024 + blockIdx.y * 16 + blockIdx.x;
  if (tid < 64) pA[blk * 128 + tid] = sA[tid];
  else if (tid < 128) pA[blk * 128 + tid] = qA[tid - 64];
}

// reducerA (batched): grid (64, 2); writes s1/b1 into stBase + z*2048.
__global__ __launch_bounds__(256) void reducerA_k(const float* __restrict__ pA,
                                                  const float* __restrict__ a1,
                                                  float* __restrict__ stBase) {
  const int tid = threadIdx.x, c = blockIdx.x, z = blockIdx.y;
  const float* pAe = pA + (size_t)z * 1024 * 128;
  float s = 0.f, q = 0.f;
  for (int i = tid; i < 1024; i += 256) {
    s += pAe[i * 128 + c];
    q += pAe[i * 128 + 64 + c];
  }
#pragma unroll
  for (int off = 32; off; off >>= 1) { s += __shfl_xor(s, off); q += __shfl_xor(q, off); }
  __shared__ float red[8];
  int wv = tid >> 6;
  if ((tid & 63) == 0) { red[wv] = s; red[4 + wv] = q; }
  __syncthreads();
  if (tid == 0) {
    float S = red[0] + red[1] + red[2] + red[3];
    float Q = red[4] + red[5] + red[6] + red[7];
    int g = c >> 3;
    float m = 0.f;
    for (int i = g; i < 8; ++i) m += a1[i];
    float mu = S * (1.f / NRED);
    float var = Q * (1.f / NRED) - mu * mu;
    float r = rsqrtf(var + EPS);
    float* stE = stBase + z * 2048;
    stE[c] = r * m;
    stE[64 + c] = -mu * r * m;
  }
}

// ---------------- convC: 4-row tile, 8 waves, T14 async shA restage ----------
// grid (8, 64, 2): z = edge. Block 512 thr = 8 waves over 4 out rows x 32 cols.
// Patch 6x34 (26KB) staged once; shA(coq+1) global loads issued into regs
// BEFORE coq's compute (latency hidden under MFMA+stats), ds_write after the
// post-compute barrier. LDS 48.6KB. (512,4): r7's (512,6) forced 40-VGPR spill
// (WRITE_SIZE 40MB); (512,4) caps 128 -> clean 52-VGPR alloc (r8: 72.2us).
__global__ __launch_bounds__(512, 4) void convC_k(const u16* __restrict__ t0,
                                                  const u16* __restrict__ t1,
                                                  const u16* __restrict__ wG64,
                                                  const u16* __restrict__ wT8,
                                                  const float* __restrict__ stBase,
                                                  float* __restrict__ pC) {
  __shared__ __align__(16) u16 shp[PATCH6];       // 26112 B
  __shared__ __align__(16) u16 shA[64 * 16 * 8];  // 16384 B (one co-quarter)
  __shared__ __align__(16) u16 shA2[8 * 16 * 8];  // 2048 B
  __shared__ float sC[4][128], qC[4][128];        // 4096 B
  const int tid = threadIdx.x;
  const int b = blockIdx.y, R0 = blockIdx.x * 4;
  const int edge = blockIdx.z;
  const u16* t = edge ? t1 : t0;
  const float* stE = stBase + edge * 2048;
  const u16* wGe = wG64 + edge * 32768;
  const u16* wT8e = wT8 + edge * 4096;
  ((float*)sC)[tid] = 0.f;
  ((float*)qC)[tid] = 0.f;
  // ---- stage 6-row affine patch (1632 chunks, 512 threads) ----
  {
    const int oct0 = tid & 7;
    float sc[8], bc[8];
#pragma unroll
    for (int j = 0; j < 8; ++j) { sc[j] = stE[oct0 * 8 + j]; bc[j] = stE[64 + oct0 * 8 + j]; }
    const u16* src = t + (size_t)b * IMST + (size_t)R0 * 2176;
#pragma unroll
    for (int i = 0; i < 4; ++i) {
      int c = i * 512 + tid;
      if (i == 3 && tid >= 96) break;
      int px = c >> 3, oct = c & 7;
      int prow = px / 34, pcol = px - prow * 34;
      bool halo = (R0 + prow == 0) || (R0 + prow == 33) || (pcol == 0) || (pcol == 33);
      uint4 o = {0u, 0u, 0u, 0u};
      if (!halo) {
        uint4 u = *(const uint4*)&src[(size_t)c * 8];
        unsigned uv[4] = {u.x, u.y, u.z, u.w};
        unsigned rv[4];
#pragma unroll
        for (int p2 = 0; p2 < 4; ++p2) {
          float lo = bf2f((u16)(uv[p2] & 0xffff)) * sc[p2 * 2] + bc[p2 * 2];
          float hi = bf2f((u16)(uv[p2] >> 16)) * sc[p2 * 2 + 1] + bc[p2 * 2 + 1];
          rv[p2] = pk2(lo, hi);
        }
        o.x = rv[0]; o.y = rv[1]; o.z = rv[2]; o.w = rv[3];
      }
      *(uint4*)&shp[SWZ(px, oct)] = o;
    }
  }
  // ---- stage shA/shA2 for coq=0 (1024 chunks / 128 chunks) ----
#pragma unroll
  for (int i = 0; i < 2; ++i) {
    int c = i * 512 + tid;
    int row = c >> 4, col = c & 15;
    *(uint4*)&shA[c * 8] = *(const uint4*)&wGe[(size_t)(row * 64 + col) * 8];
  }
  if (tid < 128) {
    int g = tid >> 4, col = tid & 15;
    *(uint4*)&shA2[tid * 8] = *(const uint4*)&wT8e[(size_t)(g * 64 + col) * 8];
  }
  __syncthreads();
  const int lane = tid & 63, w = tid >> 6;
  const int ln = lane & 15, quad = lane >> 4;
  const int lrow = w >> 1, colbase = (w & 1) * 16;
  int px[3];
#pragma unroll
  for (int ch = 0; ch < 3; ++ch) {
    int tp = ch * 4 + quad; if (tp > 8) tp = 8;
    px[ch] = (lrow + tp / 3) * 34 + colbase + ln + tp % 3;
  }
#pragma unroll 1
  for (int coq = 0; coq < 4; ++coq) {
    // T14: issue next co-quarter's weight loads into regs before compute
    uint4 wr0, wr1, wr2;
    if (coq < 3) {
      const int nq = coq + 1;
      {
        int c = tid;
        wr0 = *(const uint4*)&wGe[(size_t)((c >> 4) * 64 + nq * 16 + (c & 15)) * 8];
      }
      {
        int c = 512 + tid;
        wr1 = *(const uint4*)&wGe[(size_t)((c >> 4) * 64 + nq * 16 + (c & 15)) * 8];
      }
      if (tid < 128)
        wr2 = *(const uint4*)&wT8e[(size_t)((tid >> 4) * 64 + nq * 16 + (tid & 15)) * 8];
    }
    f32x4 acc[8];
#pragma unroll
    for (int g = 0; g < 8; ++g) acc[g] = (f32x4){0.f, 0.f, 0.f, 0.f};
#pragma unroll
    for (int g = 0; g < 8; ++g) {
#pragma unroll
      for (int ch = 0; ch < 3; ++ch) {
        bf16x8 bx = *(const bf16x8*)&shp[SWZ(px[ch], g)];
        bf16x8 aw;
        if (ch < 2) {
          aw = *(const bf16x8*)&shA[((g * 8 + ch * 4 + quad) * 16 + ln) * 8];
        } else {
          aw = (bf16x8){0, 0, 0, 0, 0, 0, 0, 0};
          if (quad == 0) aw = *(const bf16x8*)&shA2[(g * 16 + ln) * 8];
        }
        acc[g] = MFMA16(aw, bx, acc[g]);
      }
    }
    f32x4 P = (f32x4){0.f, 0.f, 0.f, 0.f};
#pragma unroll
    for (int k = 0; k < 8; ++k) {
      P += acc[k];
#pragma unroll
      for (int r = 0; r < 4; ++r) {
        float v = P[r];
        float s = row_reduce16(v);
        float q = row_reduce16(v * v);
        if (ln == 15) {
          atomicAdd(&sC[coq][k * 16 + quad * 4 + r], s);
          atomicAdd(&qC[coq][k * 16 + quad * 4 + r], q);
        }
      }
    }
    __syncthreads();  // all reads of shA/shA2 for this coq done
    if (coq < 3) {    // write prefetched regs -> LDS
      *(uint4*)&shA[(size_t)tid * 8] = wr0;
      *(uint4*)&shA[(size_t)(512 + tid) * 8] = wr1;
      if (tid < 128) *(uint4*)&shA2[tid * 8] = wr2;
      __syncthreads();
    }
  }
  __syncthreads();
  const int blk = blockIdx.y * 8 + blockIdx.x;  // 0..511
#pragma unroll 1
  for (int coq = 0; coq < 4; ++coq) {
    const size_t base = ((size_t)(edge * 4 + coq) * 512 + blk) * 256;
    if (tid < 128) pC[base + tid] = sC[coq][tid];
    else if (tid < 256) pC[base + 128 + (tid - 128)] = qC[coq][tid - 128];
  }
}

// redCprepE (batched): grid (64, 2): c, z(edge). finalizeC + fold g -> wE.
__global__ __launch_bounds__(256) void redCprepE_k(const float* __restrict__ pC,
                                                   const float* __restrict__ w2a,
                                                   const float* __restrict__ w2b,
                                                   const float* __restrict__ a1,
                                                   const float* __restrict__ a2,
                                                   float* __restrict__ stBase,
                                                   u16* __restrict__ wEbase,
                                                   float* __restrict__ cm) {
  const int tid = threadIdx.x, c = blockIdx.x, z = blockIdx.y;
  const int coq = c >> 4, cl = c & 15;
  const float* w2 = z ? w2b : w2a;
  float* stE = stBase + z * 2048;
  u16* wE = wEbase + z * 36864;
  float s[8], q[8];
#pragma unroll
  for (int k = 0; k < 8; ++k) { s[k] = 0.f; q[k] = 0.f; }
  for (int i = tid; i < 512; i += 256) {
    const float* pb = pC + ((size_t)(z * 4 + coq) * 512 + i) * 256;
#pragma unroll
    for (int k = 0; k < 8; ++k) {
      s[k] += pb[k * 16 + cl];
      q[k] += pb[128 + k * 16 + cl];
    }
  }
#pragma unroll
  for (int k = 0; k < 8; ++k) {
#pragma unroll
    for (int off = 32; off; off >>= 1) { s[k] += __shfl_xor(s[k], off); q[k] += __shfl_xor(q[k], off); }
  }
  __shared__ float red[4][16];
  __shared__ float gL[8];
  int wv = tid >> 6;
  if ((tid & 63) == 0) {
#pragma unroll
    for (int k = 0; k < 8; ++k) { red[wv][k * 2] = s[k]; red[wv][k * 2 + 1] = q[k]; }
  }
  __syncthreads();
  if (tid == 0) {
    float suf = 0.f, bias = 0.f;
    for (int k = 7; k >= 0; --k) {
      float S = red[0][k * 2] + red[1][k * 2] + red[2][k * 2] + red[3][k * 2];
      float Q = red[0][k * 2 + 1] + red[1][k * 2 + 1] + red[2][k * 2 + 1] + red[3][k * 2 + 1];
      float mu = S * (1.f / NRED);
      float var = Q * (1.f / NRED) - mu * mu;
      float rr = rsqrtf(var + EPS);
      bias -= a2[k] * mu * rr;
      suf += a2[k] * rr;
      gL[k] = suf;
    }
    stE[128 + c] = bias;
    if (z == 0) {
      int g = c >> 3;
      float m1 = 0.f, m2 = 0.f;
      for (int i = g; i < 8; ++i) { m1 += a1[i]; m2 += a2[i]; }
      cm[c] = m1 * m2;
    }
  }
  __syncthreads();
  for (int idx = tid; idx < 576; idx += 256) {
    int tap = idx >> 6, ci = idx & 63;
    wE[(tap * 64 + c) * 64 + ci] = f2bf(w2[(c * 64 + ci) * 9 + tap] * gL[ci >> 3]);
  }
}

// ---------------- convE (modes 0,1): conv2 + epilogue ------------------------
// A-fragments streamed from global per tap (same coalesced layout as convA).
// MODE 1: n1T pool neighborhood staged raw into LDS shn (r9: -14us).
template <int MODE>
__global__ __launch_bounds__(256, 4) void convE_k(const u16* __restrict__ t,
                                                  const float* __restrict__ stE,
                                                  const u16* __restrict__ wEp,
                                                  u16* __restrict__ d1,
                                                  u16* __restrict__ d2,
                                                  const float* __restrict__ cm) {
  __shared__ __align__(16) u16 shp[PATCH];
  __shared__ __align__(16) u16 shn[MODE == 1 ? PATCH : 8];
  __shared__ float cmL[64], biasL[64];
  const int tid = threadIdx.x;
  const int b = blockIdx.y, R0 = blockIdx.x * 2;
  if (tid < 64) { cmL[tid] = cm[tid]; biasL[tid] = stE[128 + tid]; }
  stage_affine(t + (size_t)b * IMST + (size_t)R0 * 2176, shp, tid, R0, stE);
  if constexpr (MODE == 1) {
    const u16* nsrc = d2 + (size_t)b * IMST + (size_t)R0 * 2176;
#pragma unroll
    for (int i = 0; i < 5; ++i) {
      int c = i * 256 + tid;
      if (i == 4 && tid >= 64) break;
      int px = c >> 3, oct = c & 7;
      *(uint4*)&shn[SWZ(px, oct)] = *(const uint4*)&nsrc[(size_t)c * 8];
    }
  }
  const int lane = tid & 63, w = tid >> 6;
  const int ln = lane & 15, quad = lane >> 4;
  const int lr = w >> 1, mh = w & 1;
  const u16* wbase = wEp + (size_t)((mh * 2) * 16 + ln) * 64 + quad * 8;
  __syncthreads();
  f32x4 acc[2][2];
#pragma unroll
  for (int m2 = 0; m2 < 2; ++m2)
#pragma unroll
    for (int nf = 0; nf < 2; ++nf) acc[m2][nf] = (f32x4){0.f, 0.f, 0.f, 0.f};
#pragma unroll 3
  for (int tap = 0; tap < 9; ++tap) {
    const int dy = tap / 3, dx = tap % 3;
    const int px0 = (lr + dy) * 34 + ln + dx;
    bf16x8 A[2][2];
#pragma unroll
    for (int m2 = 0; m2 < 2; ++m2)
#pragma unroll
      for (int h = 0; h < 2; ++h)
        A[m2][h] = *(const bf16x8*)&wbase[(size_t)(tap * 64 + m2 * 16) * 64 + h * 32];
#pragma unroll
    for (int h = 0; h < 2; ++h) {
      const int oct = h * 4 + quad;
      bf16x8 b0 = *(const bf16x8*)&shp[SWZ(px0, oct)];
      bf16x8 b1 = *(const bf16x8*)&shp[SWZ(px0 + 16, oct)];
      acc[0][0] = MFMA16(A[0][h], b0, acc[0][0]);
      acc[0][1] = MFMA16(A[0][h], b1, acc[0][1]);
      acc[1][0] = MFMA16(A[1][h], b0, acc[1][0]);
      acc[1][1] = MFMA16(A[1][h], b1, acc[1][1]);
    }
  }
  const int R = R0 + lr;
#pragma unroll
  for (int m2 = 0; m2 < 2; ++m2) {
    const int cob = (mh * 2 + m2) * 16 + quad * 4;
#pragma unroll
    for (int nf = 0; nf < 2; ++nf) {
      const int C = nf * 16 + ln;
      const size_t haloPx = (size_t)b * IMST + (size_t)((R + 1) * 34 + C + 1) * 64 + cob;
      float v[4];
#pragma unroll
      for (int r = 0; r < 4; ++r) v[r] = acc[m2][nf][r] + biasL[cob + r];
      if (MODE == 0) {
        uint2 pk, pkr;
        pk.x = pk2(v[0], v[1]); pk.y = pk2(v[2], v[3]);
        pkr.x = pk2(fmaxf(v[0], 0.f), fmaxf(v[1], 0.f));
        pkr.y = pk2(fmaxf(v[2], 0.f), fmaxf(v[3], 0.f));
        *(uint2*)&d1[haloPx] = pk;    // n1T (raw, for pool)
        *(uint2*)&d2[haloPx] = pkr;   // n1r (relu, e2 input)
      } else {
        float ps[4] = {0.f, 0.f, 0.f, 0.f};
#pragma unroll
        for (int dy = 0; dy < 3; ++dy)
#pragma unroll
          for (int dx = 0; dx < 3; ++dx) {
            const int ppx = (lr + dy) * 34 + C + dx;
            uint2 u = *(const uint2*)&shn[SWZ(ppx, cob >> 3) + (cob & 7)];
            ps[0] += bf2f((u16)(u.x & 0xffff));
            ps[1] += bf2f((u16)(u.x >> 16));
            ps[2] += bf2f((u16)(u.y & 0xffff));
            ps[3] += bf2f((u16)(u.y >> 16));
          }
        float rows = 3.f - (R == 0 ? 1.f : 0.f) - (R == 31 ? 1.f : 0.f);
        float cols = 3.f - (C == 0 ? 1.f : 0.f) - (C == 31 ? 1.f : 0.f);
        float inv = 1.f / (rows * cols);
        uint2 pkr;
        float t0v = fmaxf(v[0] + ps[0] * inv * cmL[cob], 0.f);
        float t1v = fmaxf(v[1] + ps[1] * inv * cmL[cob + 1], 0.f);
        float t2v = fmaxf(v[2] + ps[2] * inv * cmL[cob + 2], 0.f);
        float t3v = fmaxf(v[3] + ps[3] * inv * cmL[cob + 3], 0.f);
        pkr.x = pk2(t0v, t1v); pkr.y = pk2(t2v, t3v);
        *(uint2*)&d1[haloPx] = pkr;   // n2r
      }
    }
  }
}

// ---------------- convE23: fused final two convs + output --------------------
__global__ __launch_bounds__(256, 4) void convE23_k(const u16* __restrict__ t0,
                                                    const u16* __restrict__ t1,
                                                    const float* __restrict__ stBase,
                                                    const u16* __restrict__ wE2,
                                                    const u16* __restrict__ wE3,
                                                    float* __restrict__ outp,
                                                    const float* __restrict__ x,
                                                    const float* __restrict__ cm) {
  __shared__ __align__(16) u16 shp2[2 * PATCH];
  __shared__ float cmL[64], biasL[64];
  const int tid = threadIdx.x;
  const int b = blockIdx.y, R0 = blockIdx.x * 2;
  if (tid < 64) {
    cmL[tid] = cm[tid];
    biasL[tid] = stBase[128 + tid] + stBase[2048 + 128 + tid];
  }
  stage_affine(t0 + (size_t)b * IMST + (size_t)R0 * 2176, shp2, tid, R0, stBase);
  stage_affine(t1 + (size_t)b * IMST + (size_t)R0 * 2176, shp2 + PATCH, tid, R0, stBase + 2048);
  __syncthreads();
  const int lane = tid & 63, w = tid >> 6;
  const int ln = lane & 15, quad = lane >> 4;
  const int lr = w >> 1, mh = w & 1;
  f32x4 acc[2][2];
#pragma unroll
  for (int m2 = 0; m2 < 2; ++m2)
#pragma unroll
    for (int nf = 0; nf < 2; ++nf) acc[m2][nf] = (f32x4){0.f, 0.f, 0.f, 0.f};
#pragma unroll 1
  for (int ei = 0; ei < 2; ++ei) {
    const u16* wEp = ei ? wE3 : wE2;
    const u16* sp = &shp2[ei * PATCH];
    const u16* wbase = wEp + (size_t)((mh * 2) * 16 + ln) * 64 + quad * 8;
#pragma unroll 3
    for (int tap = 0; tap < 9; ++tap) {
      const int dy = tap / 3, dx = tap % 3;
      const int px0 = (lr + dy) * 34 + ln + dx;
      bf16x8 A[2][2];
#pragma unroll
      for (int m2 = 0; m2 < 2; ++m2)
#pragma unroll
        for (int h = 0; h < 2; ++h)
          A[m2][h] = *(const bf16x8*)&wbase[(size_t)(tap * 64 + m2 * 16) * 64 + h * 32];
#pragma unroll
      for (int h = 0; h < 2; ++h) {
        const int oct = h * 4 + quad;
        bf16x8 b0 = *(const bf16x8*)&sp[SWZ(px0, oct)];
        bf16x8 b1 = *(const bf16x8*)&sp[SWZ(px0 + 16, oct)];
        acc[0][0] = MFMA16(A[0][h], b0, acc[0][0]);
        acc[0][1] = MFMA16(A[0][h], b1, acc[0][1]);
        acc[1][0] = MFMA16(A[1][h], b0, acc[1][0]);
        acc[1][1] = MFMA16(A[1][h], b1, acc[1][1]);
      }
    }
  }
  const int R = R0 + lr;
#pragma unroll
  for (int m2 = 0; m2 < 2; ++m2) {
    const int cob = (mh * 2 + m2) * 16 + quad * 4;
#pragma unroll
    for (int nf = 0; nf < 2; ++nf) {
      const int C = nf * 16 + ln;
      size_t base = (size_t)b * 65536 + (size_t)cob * 1024 + R * 32 + C;
#pragma unroll
      for (int r = 0; r < 4; ++r)
        outp[base + (size_t)r * 1024] =
            acc[m2][nf][r] + biasL[cob + r] + x[base + (size_t)r * 1024] * cmL[cob + r];
    }
  }
}

extern "C" void kernel_launch(void* const* d_in, const int* in_sizes, int n_in,
                              void* d_out, int out_size, void* d_ws, size_t ws_size,
                              hipStream_t stream) {
  const float* x  = (const float*)d_in[0];
  const float* a1 = (const float*)d_in[1];
  const float* a2 = (const float*)d_in[2];
  const float* W1[4] = {(const float*)d_in[3], (const float*)d_in[5],
                        (const float*)d_in[7], (const float*)d_in[9]};
  const float* W2[4] = {(const float*)d_in[4], (const float*)d_in[6],
                        (const float*)d_in[8], (const float*)d_in[10]};
  float* out = (float*)d_out;
  char* ws = (char*)d_ws;
  const size_t HB = (size_t)IMST * 64 * 2;  // 9,469,952 B per halo buffer
  u16* xT  = (u16*)ws;
  u16* t0  = (u16*)(ws + HB);
  u16* t1  = (u16*)(ws + 2 * HB);
  u16* n1T = (u16*)(ws + 3 * HB);
  u16* n1r = (u16*)(ws + 4 * HB);
  u16* n2r = (u16*)(ws + 5 * HB);
  char* p = ws + 6 * HB;
  float* st  = (float*)p;            p += 8256 * 4;
  u16* wT1   = (u16*)p;              p += 4 * 36864 * 2;
  u16* wG64  = (u16*)p;              p += 4 * 32768 * 2;
  u16* wT8   = (u16*)p;              p += 4 * 4096 * 2;
  u16* wE    = (u16*)p;              p += 4 * 36864 * 2;
  float* pA  = (float*)p;            p += 2 * 1024 * 128 * 4;
  float* pC  = (float*)p;            // 8 * 512 * 256 * 4 = 4 MB
  float* cm  = st + 8192;

  pack_wT1_k<<<36, 256, 0, stream>>>(W1[0], W1[1], W1[2], W1[3], wT1);
  pack_wG_k<<<dim3(72, 4), 256, 0, stream>>>(W2[0], W2[1], W2[2], W2[3], wG64, wT8);
  transpose_k<<<1024, 256, 0, stream>>>(x, xT);
  zero_halo_k<<<64, 160, 0, stream>>>(n1T);

  dim3 gA(16, 64, 2), gC(8, 64, 2), gE(16, 64);
  // batch edges 0+1 (both consume xT)
  convA_k<<<gA, 256, 0, stream>>>(xT, xT, wT1, wT1 + 36864, t0, t1, pA);
  reducerA_k<<<dim3(64, 2), 256, 0, stream>>>(pA, a1, st);
  convC_k<<<gC, 512, 0, stream>>>(t0, t1, wG64, wT8, st, pC);
  redCprepE_k<<<dim3(64, 2), 256, 0, stream>>>(pC, W2[0], W2[1], a1, a2, st, wE, cm);
  convE_k<0><<<gE, 256, 0, stream>>>(t0, st, wE, n1T, n1r, cm);
  convE_k<1><<<gE, 256, 0, stream>>>(t1, st + 2048, wE + 36864, n2r, n1T, cm);
  // batch edges 2+3 (consume n1r, n2r)
  convA_k<<<gA, 256, 0, stream>>>(n1r, n2r, wT1 + 2 * 36864, wT1 + 3 * 36864, t0, t1, pA);
  reducerA_k<<<dim3(64, 2), 256, 0, stream>>>(pA, a1, st + 4096);
  convC_k<<<gC, 512, 0, stream>>>(t0, t1, wG64 + 2 * 32768, wT8 + 2 * 4096, st + 4096, pC);
  redCprepE_k<<<dim3(64, 2), 256, 0, stream>>>(pC, W2[2], W2[3], a1, a2, st + 4096,
                                               wE + 2 * 36864, cm);
  convE23_k<<<gE, 256, 0, stream>>>(t0, t1, st + 4096, wE + 2 * 36864, wE + 3 * 36864,
                                    out, x, cm);
}

// Round 12
// 423.195 us; speedup vs baseline: 1.1552x; 1.0268x over previous
//
#include <hip/hip_runtime.h>

#define EPS 1e-5f
#define NRED 65536.0f   // B*H*W = 64*32*32
#define IMST 73984      // 34*34*64 halo image stride (elements)
#define PATCH 8704      // 136 px * 64 ci (swizzled, no pad)
#define PATCH6 13056    // 204 px * 64 ci (6-row patch for convC)

typedef short bf16x8 __attribute__((ext_vector_type(8)));
typedef float f32x4 __attribute__((ext_vector_type(4)));
typedef unsigned short u16;

#define MFMA16(a, b, c) __builtin_amdgcn_mfma_f32_16x16x32_bf16(a, b, c, 0, 0, 0)
// XOR-swizzled LDS patch addressing: kills bank conflicts with zero padding.
#define SWZ(px, oct) ((px) * 64 + (((oct) ^ ((px) & 7)) * 8))

__device__ __forceinline__ u16 f2bf(float x) {  // RNE f32->bf16
  union { float f; unsigned u; } v; v.f = x;
  unsigned r = v.u + 0x7FFF + ((v.u >> 16) & 1);
  return (u16)(r >> 16);
}
__device__ __forceinline__ float bf2f(u16 h) {
  union { unsigned u; float f; } v; v.u = ((unsigned)h) << 16;
  return v.f;
}
__device__ __forceinline__ unsigned pk2(float a, float b) {
  return (unsigned)f2bf(a) | ((unsigned)f2bf(b) << 16);
}

// DPP row-shift reduce over 16-lane rows; sum valid in ln==15. Pure VALU.
template <int CTRL>
__device__ __forceinline__ float dpp_mov(float x) {
  int xi = __builtin_bit_cast(int, x);
  int r = __builtin_amdgcn_update_dpp(0, xi, CTRL, 0xF, 0xF, true);
  return __builtin_bit_cast(float, r);
}
__device__ __forceinline__ float row_reduce16(float x) {
  x += dpp_mov<0x111>(x);
  x += dpp_mov<0x112>(x);
  x += dpp_mov<0x114>(x);
  x += dpp_mov<0x118>(x);
  return x;
}

// ---- swizzled patch staging (4 rows x 34 cols x 64 ci) ----------------------
__device__ __forceinline__ void stage_mask(const u16* __restrict__ src,
                                           u16* __restrict__ shp, int tid, int R0) {
#pragma unroll
  for (int i = 0; i < 5; ++i) {
    int c = i * 256 + tid;
    if (i == 4 && tid >= 64) break;
    int px = c >> 3, oct = c & 7;
    int prow = px / 34, pcol = px - prow * 34;
    bool halo = (R0 + prow == 0) || (R0 + prow == 33) || (pcol == 0) || (pcol == 33);
    uint4 v = {0u, 0u, 0u, 0u};
    if (!halo) v = *(const uint4*)&src[(size_t)c * 8];
    *(uint4*)&shp[SWZ(px, oct)] = v;
  }
}

// Affine staging: h = t*s1[ci]+b1[ci] interior, 0 halo (renorm fused).
__device__ __forceinline__ void stage_affine(const u16* __restrict__ src,
                                             u16* __restrict__ shp, int tid, int R0,
                                             const float* __restrict__ stE) {
  const int oct0 = tid & 7;
  float s[8], bb[8];
#pragma unroll
  for (int j = 0; j < 8; ++j) { s[j] = stE[oct0 * 8 + j]; bb[j] = stE[64 + oct0 * 8 + j]; }
#pragma unroll
  for (int i = 0; i < 5; ++i) {
    int c = i * 256 + tid;
    if (i == 4 && tid >= 64) break;
    int px = c >> 3, oct = c & 7;
    int prow = px / 34, pcol = px - prow * 34;
    bool halo = (R0 + prow == 0) || (R0 + prow == 33) || (pcol == 0) || (pcol == 33);
    uint4 o = {0u, 0u, 0u, 0u};
    if (!halo) {
      uint4 u = *(const uint4*)&src[(size_t)c * 8];
      unsigned uv[4] = {u.x, u.y, u.z, u.w};
      unsigned rv[4];
#pragma unroll
      for (int p2 = 0; p2 < 4; ++p2) {
        float lo = bf2f((u16)(uv[p2] & 0xffff)) * s[p2 * 2] + bb[p2 * 2];
        float hi = bf2f((u16)(uv[p2] >> 16)) * s[p2 * 2 + 1] + bb[p2 * 2 + 1];
        rv[p2] = pk2(lo, hi);
      }
      o.x = rv[0]; o.y = rv[1]; o.z = rv[2]; o.w = rv[3];
    }
    *(uint4*)&shp[SWZ(px, oct)] = o;
  }
}

// st layout: per edge e at st+e*2048: [0,64) s1 | [64,128) b1 | [128,192) bias2.

// ---------------- prep: fused pack_wT1 + pack_wG + zero_halo + transpose -----
// All four prep tasks are independent; one dispatch instead of four removes
// ~3 launch/drain boundaries from the serial chain.
// grid: [0,36) wT1 | [36,324) wG/wT8 | [324,388) zero_halo | [388,1412) transpose
__global__ __launch_bounds__(256) void prep_k(
    const float* __restrict__ x, u16* __restrict__ xT, u16* __restrict__ n1T,
    const float* __restrict__ w10, const float* __restrict__ w11,
    const float* __restrict__ w12, const float* __restrict__ w13,
    const float* __restrict__ w20, const float* __restrict__ w21,
    const float* __restrict__ w22, const float* __restrict__ w23,
    u16* __restrict__ wT1, u16* __restrict__ wG64, u16* __restrict__ wT8) {
  __shared__ __align__(16) u16 sh[64 * 72];
  const int bid = blockIdx.x;
  const int tid = threadIdx.x;
  if (bid < 36) {
    int e = bid / 9, tap = bid % 9;
    const float* w = e == 0 ? w10 : e == 1 ? w11 : e == 2 ? w12 : w13;
    u16* dst = wT1 + e * 36864 + tap * 4096;
    for (int idx = tid; idx < 4096; idx += 256) {
      int co = idx >> 6, ci = idx & 63;
      dst[idx] = f2bf(w[(co * 64 + ci) * 9 + tap]);
    }
  } else if (bid < 324) {
    int r = bid - 36;
    int e = r / 72, bx = r % 72;
    const float* w = e == 0 ? w20 : e == 1 ? w21 : e == 2 ? w22 : w23;
    int g, tap;
    u16* dst;
    if (bx < 64) { g = bx >> 3; tap = bx & 7; dst = wG64 + e * 32768 + bx * 512; }
    else         { g = bx - 64; tap = 8;      dst = wT8 + e * 4096 + g * 512; }
    for (int idx = tid; idx < 512; idx += 256) {
      int co = idx >> 3, cig = idx & 7;
      dst[idx] = f2bf(w[(co * 64 + g * 8 + cig) * 9 + tap]);
    }
  } else if (bid < 388) {
    int b = bid - 324;
    if (tid >= 132) return;
    int R, C;
    if (tid < 34) { R = 0; C = tid; }
    else if (tid < 68) { R = 33; C = tid - 34; }
    else if (tid < 100) { R = tid - 67; C = 0; }
    else { R = tid - 99; C = 33; }
    u16* p = n1T + (size_t)b * IMST + (size_t)(R * 34 + C) * 64;
    uint4 z = {0u, 0u, 0u, 0u};
#pragma unroll
    for (int i = 0; i < 8; ++i) *(uint4*)&p[i * 8] = z;
  } else {
    const int bb = bid - 388;
    const int b = bb >> 4, slab = bb & 15;
    const int ln = tid & 63, w = tid >> 6;
    const float* xb = x + (size_t)b * 65536 + slab * 64;
#pragma unroll
    for (int i = 0; i < 16; ++i) {
      int ci = w + i * 4;
      float v = xb[ci * 1024 + ln];
      sh[ln * 72 + ci] = f2bf(fmaxf(v, 0.f));
    }
    __syncthreads();
    u16* dst = xT + (size_t)b * IMST;
#pragma unroll
    for (int j = 0; j < 2; ++j) {
      int idx = tid + j * 256;
      int p = idx >> 3, oct = idx & 7;
      int gp = slab * 64 + p;
      int R = gp >> 5, C = gp & 31;
      *(uint4*)&dst[((R + 1) * 34 + C + 1) * 64 + oct * 8] = *(const uint4*)&sh[p * 72 + oct * 8];
    }
  }
}

// ---------------- convA (2-edge batched): t = conv3x3(xin, W1) + stats -------
// A-fragments streamed from global per tap (coalesced [tap][co][ci] layout,
// L2-resident 147KB) instead of 144-VGPR register cache.
__global__ __launch_bounds__(256, 4) void convA_k(const u16* __restrict__ in0,
                                                  const u16* __restrict__ in1,
                                                  const u16* __restrict__ wTa,
                                                  const u16* __restrict__ wTb,
                                                  u16* __restrict__ t0,
                                                  u16* __restrict__ t1,
                                                  float* __restrict__ pA) {
  __shared__ __align__(16) u16 shp[PATCH];
  __shared__ float sA[64], qA[64];
  const int tid = threadIdx.x;
  const int b = blockIdx.y, R0 = blockIdx.x * 2, z = blockIdx.z;
  const u16* xin = z ? in1 : in0;
  const u16* wT = z ? wTb : wTa;
  u16* t = z ? t1 : t0;
  if (tid < 64) { sA[tid] = 0.f; qA[tid] = 0.f; }
  stage_mask(xin + (size_t)b * IMST + (size_t)R0 * 2176, shp, tid, R0);
  const int lane = tid & 63, w = tid >> 6;
  const int ln = lane & 15, quad = lane >> 4;
  const int lr = w >> 1, mh = w & 1;
  const u16* wbase = wT + (size_t)((mh * 2) * 16 + ln) * 64 + quad * 8;
  __syncthreads();
  f32x4 acc[2][2];
#pragma unroll
  for (int m2 = 0; m2 < 2; ++m2)
#pragma unroll
    for (int nf = 0; nf < 2; ++nf) acc[m2][nf] = (f32x4){0.f, 0.f, 0.f, 0.f};
#pragma unroll 3
  for (int tap = 0; tap < 9; ++tap) {
    const int dy = tap / 3, dx = tap % 3;
    const int px0 = (lr + dy) * 34 + ln + dx;
    bf16x8 A[2][2];
#pragma unroll
    for (int m2 = 0; m2 < 2; ++m2)
#pragma unroll
      for (int h = 0; h < 2; ++h)
        A[m2][h] = *(const bf16x8*)&wbase[(size_t)(tap * 64 + m2 * 16) * 64 + h * 32];
#pragma unroll
    for (int h = 0; h < 2; ++h) {
      const int oct = h * 4 + quad;
      bf16x8 b0 = *(const bf16x8*)&shp[SWZ(px0, oct)];
      bf16x8 b1 = *(const bf16x8*)&shp[SWZ(px0 + 16, oct)];
      acc[0][0] = MFMA16(A[0][h], b0, acc[0][0]);
      acc[0][1] = MFMA16(A[0][h], b1, acc[0][1]);
      acc[1][0] = MFMA16(A[1][h], b0, acc[1][0]);
      acc[1][1] = MFMA16(A[1][h], b1, acc[1][1]);
    }
  }
  const int R = R0 + lr;
#pragma unroll
  for (int m2 = 0; m2 < 2; ++m2) {
    const int cob = (mh * 2 + m2) * 16 + quad * 4;
#pragma unroll
    for (int nf = 0; nf < 2; ++nf) {
      u16* tb = t + (size_t)b * IMST + (size_t)((R + 1) * 34 + nf * 16 + ln + 1) * 64 + cob;
      uint2 pk;
      pk.x = pk2(acc[m2][nf][0], acc[m2][nf][1]);
      pk.y = pk2(acc[m2][nf][2], acc[m2][nf][3]);
      *(uint2*)tb = pk;
    }
#pragma unroll
    for (int r = 0; r < 4; ++r) {
      float v0 = acc[m2][0][r], v1 = acc[m2][1][r];
      float s = row_reduce16(v0) + row_reduce16(v1);
      float q = row_reduce16(v0 * v0) + row_reduce16(v1 * v1);
      if (ln == 15) {
        atomicAdd(&sA[cob + r], s);
        atomicAdd(&qA[cob + r], q);
      }
    }
  }
  __syncthreads();
  const int blk = z * 1024 + blockIdx.y * 16 + blockIdx.x;
  if (tid < 64) pA[blk * 128 + tid] = sA[tid];
  else if (tid < 128) pA[blk * 128 + tid] = qA[tid - 64];
}

// reducerA (batched): grid (64, 2); writes s1/b1 into stBase + z*2048.
__global__ __launch_bounds__(256) void reducerA_k(const float* __restrict__ pA,
                                                  const float* __restrict__ a1,
                                                  float* __restrict__ stBase) {
  const int tid = threadIdx.x, c = blockIdx.x, z = blockIdx.y;
  const float* pAe = pA + (size_t)z * 1024 * 128;
  float s = 0.f, q = 0.f;
  for (int i = tid; i < 1024; i += 256) {
    s += pAe[i * 128 + c];
    q += pAe[i * 128 + 64 + c];
  }
#pragma unroll
  for (int off = 32; off; off >>= 1) { s += __shfl_xor(s, off); q += __shfl_xor(q, off); }
  __shared__ float red[8];
  int wv = tid >> 6;
  if ((tid & 63) == 0) { red[wv] = s; red[4 + wv] = q; }
  __syncthreads();
  if (tid == 0) {
    float S = red[0] + red[1] + red[2] + red[3];
    float Q = red[4] + red[5] + red[6] + red[7];
    int g = c >> 3;
    float m = 0.f;
    for (int i = g; i < 8; ++i) m += a1[i];
    float mu = S * (1.f / NRED);
    float var = Q * (1.f / NRED) - mu * mu;
    float r = rsqrtf(var + EPS);
    float* stE = stBase + z * 2048;
    stE[c] = r * m;
    stE[64 + c] = -mu * r * m;
  }
}

// ---------------- convC: 4-row tile, 8 waves, T14 async shA restage ----------
// grid (8, 64, 2): z = edge. Block 512 thr = 8 waves over 4 out rows x 32 cols.
// Patch 6x34 (26KB) staged once; shA(coq+1) global loads issued into regs
// BEFORE coq's compute (latency hidden under MFMA+stats), ds_write after the
// post-compute barrier. LDS 48.6KB. (512,4): r7's (512,6) forced 40-VGPR spill
// (WRITE_SIZE 40MB); (512,4) caps 128 -> clean 52-VGPR alloc (r8: 72.2us).
__global__ __launch_bounds__(512, 4) void convC_k(const u16* __restrict__ t0,
                                                  const u16* __restrict__ t1,
                                                  const u16* __restrict__ wG64,
                                                  const u16* __restrict__ wT8,
                                                  const float* __restrict__ stBase,
                                                  float* __restrict__ pC) {
  __shared__ __align__(16) u16 shp[PATCH6];       // 26112 B
  __shared__ __align__(16) u16 shA[64 * 16 * 8];  // 16384 B (one co-quarter)
  __shared__ __align__(16) u16 shA2[8 * 16 * 8];  // 2048 B
  __shared__ float sC[4][128], qC[4][128];        // 4096 B
  const int tid = threadIdx.x;
  const int b = blockIdx.y, R0 = blockIdx.x * 4;
  const int edge = blockIdx.z;
  const u16* t = edge ? t1 : t0;
  const float* stE = stBase + edge * 2048;
  const u16* wGe = wG64 + edge * 32768;
  const u16* wT8e = wT8 + edge * 4096;
  ((float*)sC)[tid] = 0.f;
  ((float*)qC)[tid] = 0.f;
  // ---- stage 6-row affine patch (1632 chunks, 512 threads) ----
  {
    const int oct0 = tid & 7;
    float sc[8], bc[8];
#pragma unroll
    for (int j = 0; j < 8; ++j) { sc[j] = stE[oct0 * 8 + j]; bc[j] = stE[64 + oct0 * 8 + j]; }
    const u16* src = t + (size_t)b * IMST + (size_t)R0 * 2176;
#pragma unroll
    for (int i = 0; i < 4; ++i) {
      int c = i * 512 + tid;
      if (i == 3 && tid >= 96) break;
      int px = c >> 3, oct = c & 7;
      int prow = px / 34, pcol = px - prow * 34;
      bool halo = (R0 + prow == 0) || (R0 + prow == 33) || (pcol == 0) || (pcol == 33);
      uint4 o = {0u, 0u, 0u, 0u};
      if (!halo) {
        uint4 u = *(const uint4*)&src[(size_t)c * 8];
        unsigned uv[4] = {u.x, u.y, u.z, u.w};
        unsigned rv[4];
#pragma unroll
        for (int p2 = 0; p2 < 4; ++p2) {
          float lo = bf2f((u16)(uv[p2] & 0xffff)) * sc[p2 * 2] + bc[p2 * 2];
          float hi = bf2f((u16)(uv[p2] >> 16)) * sc[p2 * 2 + 1] + bc[p2 * 2 + 1];
          rv[p2] = pk2(lo, hi);
        }
        o.x = rv[0]; o.y = rv[1]; o.z = rv[2]; o.w = rv[3];
      }
      *(uint4*)&shp[SWZ(px, oct)] = o;
    }
  }
  // ---- stage shA/shA2 for coq=0 (1024 chunks / 128 chunks) ----
#pragma unroll
  for (int i = 0; i < 2; ++i) {
    int c = i * 512 + tid;
    int row = c >> 4, col = c & 15;
    *(uint4*)&shA[c * 8] = *(const uint4*)&wGe[(size_t)(row * 64 + col) * 8];
  }
  if (tid < 128) {
    int g = tid >> 4, col = tid & 15;
    *(uint4*)&shA2[tid * 8] = *(const uint4*)&wT8e[(size_t)(g * 64 + col) * 8];
  }
  __syncthreads();
  const int lane = tid & 63, w = tid >> 6;
  const int ln = lane & 15, quad = lane >> 4;
  const int lrow = w >> 1, colbase = (w & 1) * 16;
  int px[3];
#pragma unroll
  for (int ch = 0; ch < 3; ++ch) {
    int tp = ch * 4 + quad; if (tp > 8) tp = 8;
    px[ch] = (lrow + tp / 3) * 34 + colbase + ln + tp % 3;
  }
#pragma unroll 1
  for (int coq = 0; coq < 4; ++coq) {
    // T14: issue next co-quarter's weight loads into regs before compute
    uint4 wr0, wr1, wr2;
    if (coq < 3) {
      const int nq = coq + 1;
      {
        int c = tid;
        wr0 = *(const uint4*)&wGe[(size_t)((c >> 4) * 64 + nq * 16 + (c & 15)) * 8];
      }
      {
        int c = 512 + tid;
        wr1 = *(const uint4*)&wGe[(size_t)((c >> 4) * 64 + nq * 16 + (c & 15)) * 8];
      }
      if (tid < 128)
        wr2 = *(const uint4*)&wT8e[(size_t)((tid >> 4) * 64 + nq * 16 + (tid & 15)) * 8];
    }
    f32x4 acc[8];
#pragma unroll
    for (int g = 0; g < 8; ++g) acc[g] = (f32x4){0.f, 0.f, 0.f, 0.f};
#pragma unroll
    for (int g = 0; g < 8; ++g) {
#pragma unroll
      for (int ch = 0; ch < 3; ++ch) {
        bf16x8 bx = *(const bf16x8*)&shp[SWZ(px[ch], g)];
        bf16x8 aw;
        if (ch < 2) {
          aw = *(const bf16x8*)&shA[((g * 8 + ch * 4 + quad) * 16 + ln) * 8];
        } else {
          aw = (bf16x8){0, 0, 0, 0, 0, 0, 0, 0};
          if (quad == 0) aw = *(const bf16x8*)&shA2[(g * 16 + ln) * 8];
        }
        acc[g] = MFMA16(aw, bx, acc[g]);
      }
    }
    f32x4 P = (f32x4){0.f, 0.f, 0.f, 0.f};
#pragma unroll
    for (int k = 0; k < 8; ++k) {
      P += acc[k];
#pragma unroll
      for (int r = 0; r < 4; ++r) {
        float v = P[r];
        float s = row_reduce16(v);
        float q = row_reduce16(v * v);
        if (ln == 15) {
          atomicAdd(&sC[coq][k * 16 + quad * 4 + r], s);
          atomicAdd(&qC[coq][k * 16 + quad * 4 + r], q);
        }
      }
    }
    __syncthreads();  // all reads of shA/shA2 for this coq done
    if (coq < 3) {    // write prefetched regs -> LDS
      *(uint4*)&shA[(size_t)tid * 8] = wr0;
      *(uint4*)&shA[(size_t)(512 + tid) * 8] = wr1;
      if (tid < 128) *(uint4*)&shA2[tid * 8] = wr2;
      __syncthreads();
    }
  }
  __syncthreads();
  const int blk = blockIdx.y * 8 + blockIdx.x;  // 0..511
#pragma unroll 1
  for (int coq = 0; coq < 4; ++coq) {
    const size_t base = ((size_t)(edge * 4 + coq) * 512 + blk) * 256;
    if (tid < 128) pC[base + tid] = sC[coq][tid];
    else if (tid < 256) pC[base + 128 + (tid - 128)] = qC[coq][tid - 128];
  }
}

// redCprepE (batched): grid (64, 2): c, z(edge). finalizeC + fold g -> wE.
__global__ __launch_bounds__(256) void redCprepE_k(const float* __restrict__ pC,
                                                   const float* __restrict__ w2a,
                                                   const float* __restrict__ w2b,
                                                   const float* __restrict__ a1,
                                                   const float* __restrict__ a2,
                                                   float* __restrict__ stBase,
                                                   u16* __restrict__ wEbase,
                                                   float* __restrict__ cm) {
  const int tid = threadIdx.x, c = blockIdx.x, z = blockIdx.y;
  const int coq = c >> 4, cl = c & 15;
  const float* w2 = z ? w2b : w2a;
  float* stE = stBase + z * 2048;
  u16* wE = wEbase + z * 36864;
  float s[8], q[8];
#pragma unroll
  for (int k = 0; k < 8; ++k) { s[k] = 0.f; q[k] = 0.f; }
  for (int i = tid; i < 512; i += 256) {
    const float* pb = pC + ((size_t)(z * 4 + coq) * 512 + i) * 256;
#pragma unroll
    for (int k = 0; k < 8; ++k) {
      s[k] += pb[k * 16 + cl];
      q[k] += pb[128 + k * 16 + cl];
    }
  }
#pragma unroll
  for (int k = 0; k < 8; ++k) {
#pragma unroll
    for (int off = 32; off; off >>= 1) { s[k] += __shfl_xor(s[k], off); q[k] += __shfl_xor(q[k], off); }
  }
  __shared__ float red[4][16];
  __shared__ float gL[8];
  int wv = tid >> 6;
  if ((tid & 63) == 0) {
#pragma unroll
    for (int k = 0; k < 8; ++k) { red[wv][k * 2] = s[k]; red[wv][k * 2 + 1] = q[k]; }
  }
  __syncthreads();
  if (tid == 0) {
    float suf = 0.f, bias = 0.f;
    for (int k = 7; k >= 0; --k) {
      float S = red[0][k * 2] + red[1][k * 2] + red[2][k * 2] + red[3][k * 2];
      float Q = red[0][k * 2 + 1] + red[1][k * 2 + 1] + red[2][k * 2 + 1] + red[3][k * 2 + 1];
      float mu = S * (1.f / NRED);
      float var = Q * (1.f / NRED) - mu * mu;
      float rr = rsqrtf(var + EPS);
      bias -= a2[k] * mu * rr;
      suf += a2[k] * rr;
      gL[k] = suf;
    }
    stE[128 + c] = bias;
    if (z == 0) {
      int g = c >> 3;
      float m1 = 0.f, m2 = 0.f;
      for (int i = g; i < 8; ++i) { m1 += a1[i]; m2 += a2[i]; }
      cm[c] = m1 * m2;
    }
  }
  __syncthreads();
  for (int idx = tid; idx < 576; idx += 256) {
    int tap = idx >> 6, ci = idx & 63;
    wE[(tap * 64 + c) * 64 + ci] = f2bf(w2[(c * 64 + ci) * 9 + tap] * gL[ci >> 3]);
  }
}

// ---------------- convE (modes 0,1): conv2 + epilogue ------------------------
// A-fragments streamed from global per tap (same coalesced layout as convA).
// MODE 1: n1T pool neighborhood staged raw into LDS shn (r9: -14us).
template <int MODE>
__global__ __launch_bounds__(256, 4) void convE_k(const u16* __restrict__ t,
                                                  const float* __restrict__ stE,
                                                  const u16* __restrict__ wEp,
                                                  u16* __restrict__ d1,
                                                  u16* __restrict__ d2,
                                                  const float* __restrict__ cm) {
  __shared__ __align__(16) u16 shp[PATCH];
  __shared__ __align__(16) u16 shn[MODE == 1 ? PATCH : 8];
  __shared__ float cmL[64], biasL[64];
  const int tid = threadIdx.x;
  const int b = blockIdx.y, R0 = blockIdx.x * 2;
  if (tid < 64) { cmL[tid] = cm[tid]; biasL[tid] = stE[128 + tid]; }
  stage_affine(t + (size_t)b * IMST + (size_t)R0 * 2176, shp, tid, R0, stE);
  if constexpr (MODE == 1) {
    const u16* nsrc = d2 + (size_t)b * IMST + (size_t)R0 * 2176;
#pragma unroll
    for (int i = 0; i < 5; ++i) {
      int c = i * 256 + tid;
      if (i == 4 && tid >= 64) break;
      int px = c >> 3, oct = c & 7;
      *(uint4*)&shn[SWZ(px, oct)] = *(const uint4*)&nsrc[(size_t)c * 8];
    }
  }
  const int lane = tid & 63, w = tid >> 6;
  const int ln = lane & 15, quad = lane >> 4;
  const int lr = w >> 1, mh = w & 1;
  const u16* wbase = wEp + (size_t)((mh * 2) * 16 + ln) * 64 + quad * 8;
  __syncthreads();
  f32x4 acc[2][2];
#pragma unroll
  for (int m2 = 0; m2 < 2; ++m2)
#pragma unroll
    for (int nf = 0; nf < 2; ++nf) acc[m2][nf] = (f32x4){0.f, 0.f, 0.f, 0.f};
#pragma unroll 3
  for (int tap = 0; tap < 9; ++tap) {
    const int dy = tap / 3, dx = tap % 3;
    const int px0 = (lr + dy) * 34 + ln + dx;
    bf16x8 A[2][2];
#pragma unroll
    for (int m2 = 0; m2 < 2; ++m2)
#pragma unroll
      for (int h = 0; h < 2; ++h)
        A[m2][h] = *(const bf16x8*)&wbase[(size_t)(tap * 64 + m2 * 16) * 64 + h * 32];
#pragma unroll
    for (int h = 0; h < 2; ++h) {
      const int oct = h * 4 + quad;
      bf16x8 b0 = *(const bf16x8*)&shp[SWZ(px0, oct)];
      bf16x8 b1 = *(const bf16x8*)&shp[SWZ(px0 + 16, oct)];
      acc[0][0] = MFMA16(A[0][h], b0, acc[0][0]);
      acc[0][1] = MFMA16(A[0][h], b1, acc[0][1]);
      acc[1][0] = MFMA16(A[1][h], b0, acc[1][0]);
      acc[1][1] = MFMA16(A[1][h], b1, acc[1][1]);
    }
  }
  const int R = R0 + lr;
#pragma unroll
  for (int m2 = 0; m2 < 2; ++m2) {
    const int cob = (mh * 2 + m2) * 16 + quad * 4;
#pragma unroll
    for (int nf = 0; nf < 2; ++nf) {
      const int C = nf * 16 + ln;
      const size_t haloPx = (size_t)b * IMST + (size_t)((R + 1) * 34 + C + 1) * 64 + cob;
      float v[4];
#pragma unroll
      for (int r = 0; r < 4; ++r) v[r] = acc[m2][nf][r] + biasL[cob + r];
      if (MODE == 0) {
        uint2 pk, pkr;
        pk.x = pk2(v[0], v[1]); pk.y = pk2(v[2], v[3]);
        pkr.x = pk2(fmaxf(v[0], 0.f), fmaxf(v[1], 0.f));
        pkr.y = pk2(fmaxf(v[2], 0.f), fmaxf(v[3], 0.f));
        *(uint2*)&d1[haloPx] = pk;    // n1T (raw, for pool)
        *(uint2*)&d2[haloPx] = pkr;   // n1r (relu, e2 input)
      } else {
        float ps[4] = {0.f, 0.f, 0.f, 0.f};
#pragma unroll
        for (int dy = 0; dy < 3; ++dy)
#pragma unroll
          for (int dx = 0; dx < 3; ++dx) {
            const int ppx = (lr + dy) * 34 + C + dx;
            uint2 u = *(const uint2*)&shn[SWZ(ppx, cob >> 3) + (cob & 7)];
            ps[0] += bf2f((u16)(u.x & 0xffff));
            ps[1] += bf2f((u16)(u.x >> 16));
            ps[2] += bf2f((u16)(u.y & 0xffff));
            ps[3] += bf2f((u16)(u.y >> 16));
          }
        float rows = 3.f - (R == 0 ? 1.f : 0.f) - (R == 31 ? 1.f : 0.f);
        float cols = 3.f - (C == 0 ? 1.f : 0.f) - (C == 31 ? 1.f : 0.f);
        float inv = 1.f / (rows * cols);
        uint2 pkr;
        float t0v = fmaxf(v[0] + ps[0] * inv * cmL[cob], 0.f);
        float t1v = fmaxf(v[1] + ps[1] * inv * cmL[cob + 1], 0.f);
        float t2v = fmaxf(v[2] + ps[2] * inv * cmL[cob + 2], 0.f);
        float t3v = fmaxf(v[3] + ps[3] * inv * cmL[cob + 3], 0.f);
        pkr.x = pk2(t0v, t1v); pkr.y = pk2(t2v, t3v);
        *(uint2*)&d1[haloPx] = pkr;   // n2r
      }
    }
  }
}

// ---------------- convE23: fused final two convs + output --------------------
__global__ __launch_bounds__(256, 4) void convE23_k(const u16* __restrict__ t0,
                                                    const u16* __restrict__ t1,
                                                    const float* __restrict__ stBase,
                                                    const u16* __restrict__ wE2,
                                                    const u16* __restrict__ wE3,
                                                    float* __restrict__ outp,
                                                    const float* __restrict__ x,
                                                    const float* __restrict__ cm) {
  __shared__ __align__(16) u16 shp2[2 * PATCH];
  __shared__ float cmL[64], biasL[64];
  const int tid = threadIdx.x;
  const int b = blockIdx.y, R0 = blockIdx.x * 2;
  if (tid < 64) {
    cmL[tid] = cm[tid];
    biasL[tid] = stBase[128 + tid] + stBase[2048 + 128 + tid];
  }
  stage_affine(t0 + (size_t)b * IMST + (size_t)R0 * 2176, shp2, tid, R0, stBase);
  stage_affine(t1 + (size_t)b * IMST + (size_t)R0 * 2176, shp2 + PATCH, tid, R0, stBase + 2048);
  __syncthreads();
  const int lane = tid & 63, w = tid >> 6;
  const int ln = lane & 15, quad = lane >> 4;
  const int lr = w >> 1, mh = w & 1;
  f32x4 acc[2][2];
#pragma unroll
  for (int m2 = 0; m2 < 2; ++m2)
#pragma unroll
    for (int nf = 0; nf < 2; ++nf) acc[m2][nf] = (f32x4){0.f, 0.f, 0.f, 0.f};
#pragma unroll 1
  for (int ei = 0; ei < 2; ++ei) {
    const u16* wEp = ei ? wE3 : wE2;
    const u16* sp = &shp2[ei * PATCH];
    const u16* wbase = wEp + (size_t)((mh * 2) * 16 + ln) * 64 + quad * 8;
#pragma unroll 3
    for (int tap = 0; tap < 9; ++tap) {
      const int dy = tap / 3, dx = tap % 3;
      const int px0 = (lr + dy) * 34 + ln + dx;
      bf16x8 A[2][2];
#pragma unroll
      for (int m2 = 0; m2 < 2; ++m2)
#pragma unroll
        for (int h = 0; h < 2; ++h)
          A[m2][h] = *(const bf16x8*)&wbase[(size_t)(tap * 64 + m2 * 16) * 64 + h * 32];
#pragma unroll
      for (int h = 0; h < 2; ++h) {
        const int oct = h * 4 + quad;
        bf16x8 b0 = *(const bf16x8*)&sp[SWZ(px0, oct)];
        bf16x8 b1 = *(const bf16x8*)&sp[SWZ(px0 + 16, oct)];
        acc[0][0] = MFMA16(A[0][h], b0, acc[0][0]);
        acc[0][1] = MFMA16(A[0][h], b1, acc[0][1]);
        acc[1][0] = MFMA16(A[1][h], b0, acc[1][0]);
        acc[1][1] = MFMA16(A[1][h], b1, acc[1][1]);
      }
    }
  }
  const int R = R0 + lr;
#pragma unroll
  for (int m2 = 0; m2 < 2; ++m2) {
    const int cob = (mh * 2 + m2) * 16 + quad * 4;
#pragma unroll
    for (int nf = 0; nf < 2; ++nf) {
      const int C = nf * 16 + ln;
      size_t base = (size_t)b * 65536 + (size_t)cob * 1024 + R * 32 + C;
#pragma unroll
      for (int r = 0; r < 4; ++r)
        outp[base + (size_t)r * 1024] =
            acc[m2][nf][r] + biasL[cob + r] + x[base + (size_t)r * 1024] * cmL[cob + r];
    }
  }
}

extern "C" void kernel_launch(void* const* d_in, const int* in_sizes, int n_in,
                              void* d_out, int out_size, void* d_ws, size_t ws_size,
                              hipStream_t stream) {
  const float* x  = (const float*)d_in[0];
  const float* a1 = (const float*)d_in[1];
  const float* a2 = (const float*)d_in[2];
  const float* W1[4] = {(const float*)d_in[3], (const float*)d_in[5],
                        (const float*)d_in[7], (const float*)d_in[9]};
  const float* W2[4] = {(const float*)d_in[4], (const float*)d_in[6],
                        (const float*)d_in[8], (const float*)d_in[10]};
  float* out = (float*)d_out;
  char* ws = (char*)d_ws;
  const size_t HB = (size_t)IMST * 64 * 2;  // 9,469,952 B per halo buffer
  u16* xT  = (u16*)ws;
  u16* t0  = (u16*)(ws + HB);
  u16* t1  = (u16*)(ws + 2 * HB);
  u16* n1T = (u16*)(ws + 3 * HB);
  u16* n1r = (u16*)(ws + 4 * HB);
  u16* n2r = (u16*)(ws + 5 * HB);
  char* p = ws + 6 * HB;
  float* st  = (float*)p;            p += 8256 * 4;
  u16* wT1   = (u16*)p;              p += 4 * 36864 * 2;
  u16* wG64  = (u16*)p;              p += 4 * 32768 * 2;
  u16* wT8   = (u16*)p;              p += 4 * 4096 * 2;
  u16* wE    = (u16*)p;              p += 4 * 36864 * 2;
  float* pA  = (float*)p;            p += 2 * 1024 * 128 * 4;
  float* pC  = (float*)p;            // 8 * 512 * 256 * 4 = 4 MB
  float* cm  = st + 8192;

  // fused prep: packs + zero_halo + transpose in one dispatch
  prep_k<<<1412, 256, 0, stream>>>(x, xT, n1T,
                                   W1[0], W1[1], W1[2], W1[3],
                                   W2[0], W2[1], W2[2], W2[3],
                                   wT1, wG64, wT8);

  dim3 gA(16, 64, 2), gC(8, 64, 2), gE(16, 64);
  // batch edges 0+1 (both consume xT)
  convA_k<<<gA, 256, 0, stream>>>(xT, xT, wT1, wT1 + 36864, t0, t1, pA);
  reducerA_k<<<dim3(64, 2), 256, 0, stream>>>(pA, a1, st);
  convC_k<<<gC, 512, 0, stream>>>(t0, t1, wG64, wT8, st, pC);
  redCprepE_k<<<dim3(64, 2), 256, 0, stream>>>(pC, W2[0], W2[1], a1, a2, st, wE, cm);
  convE_k<0><<<gE, 256, 0, stream>>>(t0, st, wE, n1T, n1r, cm);
  convE_k<1><<<gE, 256, 0, stream>>>(t1, st + 2048, wE + 36864, n2r, n1T, cm);
  // batch edges 2+3 (consume n1r, n2r)
  convA_k<<<gA, 256, 0, stream>>>(n1r, n2r, wT1 + 2 * 36864, wT1 + 3 * 36864, t0, t1, pA);
  reducerA_k<<<dim3(64, 2), 256, 0, stream>>>(pA, a1, st + 4096);
  convC_k<<<gC, 512, 0, stream>>>(t0, t1, wG64 + 2 * 32768, wT8 + 2 * 4096, st + 4096, pC);
  redCprepE_k<<<dim3(64, 2), 256, 0, stream>>>(pC, W2[2], W2[3], a1, a2, st + 4096,
                                               wE + 2 * 36864, cm);
  convE23_k<<<gE, 256, 0, stream>>>(t0, t1, st + 4096, wE + 2 * 36864, wE + 3 * 36864,
                                    out, x, cm);
}